// Round 8
// baseline (7548.548 us; speedup 1.0000x reference)
//
#include <hip/hip_runtime.h>
#include <stdint.h>

#define FH 38
#define FW 63
#define NPOS 2394           // 38*63
#define NANCH 21546         // NPOS*9
#define HIMG 608
#define WIMG 1008
#define PRE 2000
#define POST 300

typedef __attribute__((ext_vector_type(8))) short bf16x8;
typedef __attribute__((ext_vector_type(4))) float f32x4;

__device__ __constant__ float c_AB[9][4] = {
  {-37.254833f,-82.50967f,53.254833f,98.50967f},
  {-82.50967f,-173.01933f,98.50967f,189.01933f},
  {-173.01933f,-354.03867f,189.01933f,370.03867f},
  {-56.f,-56.f,72.f,72.f},
  {-120.f,-120.f,136.f,136.f},
  {-248.f,-248.f,264.f,264.f},
  {-82.50967f,-37.254833f,98.50967f,53.254833f},
  {-173.01933f,-82.50967f,189.01933f,98.50967f},
  {-354.03867f,-173.01933f,370.03867f,189.01933f}};

__device__ __forceinline__ unsigned short f2bf(float f) {
  unsigned u = __float_as_uint(f);
  u += 0x7FFFu + ((u >> 16) & 1u);
  return (unsigned short)(u >> 16);
}

// ---------------- im2col for the 16x16 stride-16 extractor ----------------
__global__ __launch_bounds__(256) void k_imext(const float* __restrict__ x, float* __restrict__ im) {
  int idx = blockIdx.x * 256 + threadIdx.x;
  if (idx >= NPOS * 768) return;
  int p = idx / 768, k = idx - p * 768;
  int ci = k >> 8, r = k & 255, ky = r >> 4, kx = r & 15;
  int py = p / FW, px = p - py * FW;
  im[idx] = x[((size_t)ci * HIMG + py * 16 + ky) * WIMG + px * 16 + kx];
}

// ---------------- split-K fp32 GEMM, 8x8/thread: A[M][K] * B[512][K]^T -> P[z][M][512] ----
// BM=128, BN=128, 256 threads. Staging identical in structure to the proven 8x4
// kernel (no fused im2col — that was R6's VGPR explosion). __launch_bounds__(256,4)
// caps VGPR at 128 (4 waves/SIMD) at compile time.
// Bank math: stores 2-way (free); A-reads 16-way broadcast (free); B-reads 4-way
// (1.58x on ~half the LDS cycles). Per k: 128 FMA-cyc vs ~62 LDS-cyc -> VALU-bound.
__global__ __launch_bounds__(256, 4) void k_gemm_sk8(
    const float* __restrict__ A, const float* __restrict__ B,
    float* __restrict__ P, int M, int K, int Kc)
{
  __shared__ float As[16][132];
  __shared__ float Bs[16][132];
  int tid = threadIdx.x;
  int bm = blockIdx.x * 128, bn = blockIdx.y * 128;
  int k0 = blockIdx.z * Kc, kend = k0 + Kc;
  int tx = tid & 15, ty = tid >> 4;
  int lr = tid >> 1, lk = (tid & 1) * 8;
  int ar = bm + lr; if (ar >= M) ar = M - 1;
  const float* ap = A + (size_t)ar * K + lk;
  const float* bp = B + (size_t)(bn + lr) * K + lk;   // bn+lr <= 511 always
  float4 ra0 = *(const float4*)(ap + k0);
  float4 ra1 = *(const float4*)(ap + k0 + 4);
  float4 rb0 = *(const float4*)(bp + k0);
  float4 rb1 = *(const float4*)(bp + k0 + 4);
  f32x4 acc[8][2];
  #pragma unroll
  for (int i = 0; i < 8; ++i) { acc[i][0] = (f32x4){0,0,0,0}; acc[i][1] = (f32x4){0,0,0,0}; }
  for (; k0 < kend; k0 += 16) {
    As[lk + 0][lr] = ra0.x; As[lk + 1][lr] = ra0.y; As[lk + 2][lr] = ra0.z; As[lk + 3][lr] = ra0.w;
    As[lk + 4][lr] = ra1.x; As[lk + 5][lr] = ra1.y; As[lk + 6][lr] = ra1.z; As[lk + 7][lr] = ra1.w;
    Bs[lk + 0][lr] = rb0.x; Bs[lk + 1][lr] = rb0.y; Bs[lk + 2][lr] = rb0.z; Bs[lk + 3][lr] = rb0.w;
    Bs[lk + 4][lr] = rb1.x; Bs[lk + 5][lr] = rb1.y; Bs[lk + 6][lr] = rb1.z; Bs[lk + 7][lr] = rb1.w;
    __syncthreads();
    if (k0 + 16 < kend) {
      ra0 = *(const float4*)(ap + k0 + 16);
      ra1 = *(const float4*)(ap + k0 + 20);
      rb0 = *(const float4*)(bp + k0 + 16);
      rb1 = *(const float4*)(bp + k0 + 20);
    }
    #pragma unroll
    for (int k = 0; k < 16; ++k) {
      float4 aL = *(const float4*)&As[k][ty * 8];
      float4 aH = *(const float4*)&As[k][ty * 8 + 4];
      float4 bL = *(const float4*)&Bs[k][tx * 8];
      float4 bH = *(const float4*)&Bs[k][tx * 8 + 4];
      float av[8] = {aL.x, aL.y, aL.z, aL.w, aH.x, aH.y, aH.z, aH.w};
      #pragma unroll
      for (int i = 0; i < 8; ++i) {
        acc[i][0][0] += av[i] * bL.x; acc[i][0][1] += av[i] * bL.y;
        acc[i][0][2] += av[i] * bL.z; acc[i][0][3] += av[i] * bL.w;
        acc[i][1][0] += av[i] * bH.x; acc[i][1][1] += av[i] * bH.y;
        acc[i][1][2] += av[i] * bH.z; acc[i][1][3] += av[i] * bH.w;
      }
    }
    __syncthreads();
  }
  float* Pp = P + (size_t)blockIdx.z * M * 512;
  #pragma unroll
  for (int i = 0; i < 8; ++i) {
    int m = bm + ty * 8 + i;
    if (m < M) {
      *(f32x4*)&Pp[(size_t)m * 512 + bn + tx * 8]     = acc[i][0];
      *(f32x4*)&Pp[(size_t)m * 512 + bn + tx * 8 + 4] = acc[i][1];
    }
  }
}

// ---------------- reduce split-K conv partials (+bias, relu) ----------------
template<bool BIAS, int S>
__global__ __launch_bounds__(256) void k_reduce_conv(
    const float* __restrict__ P, const float* __restrict__ bias,
    float* __restrict__ C, int M)
{
  int i = blockIdx.x * 256 + threadIdx.x;      // float4 index
  int total = M * 128;                          // M*512/4
  if (i >= total) return;
  size_t stride = (size_t)M * 512;
  float4 s = make_float4(0.f, 0.f, 0.f, 0.f);
  if (BIAS) s = *(const float4*)&bias[(i * 4) & 511];
  #pragma unroll
  for (int s2 = 0; s2 < S; ++s2) {
    float4 v = *(const float4*)&P[s2 * stride + (size_t)i * 4];
    s.x += v.x; s.y += v.y; s.z += v.z; s.w += v.w;
  }
  s.x = fmaxf(s.x, 0.f); s.y = fmaxf(s.y, 0.f); s.z = fmaxf(s.z, 0.f); s.w = fmaxf(s.w, 0.f);
  *(float4*)&C[(size_t)i * 4] = s;
}

// ---------------- transpose [NPOS][512] -> [512][NPOS] ----------------
__global__ __launch_bounds__(256) void k_transpose(const float* __restrict__ in, float* __restrict__ out) {
  __shared__ float t[32][33];
  int tx = threadIdx.x & 31, ty = threadIdx.x >> 5;
  int p0 = blockIdx.x * 32, c0 = blockIdx.y * 32;
  #pragma unroll
  for (int i = 0; i < 4; ++i) {
    int p = p0 + ty + i * 8;
    if (p < NPOS) t[ty + i * 8][tx] = in[(size_t)p * 512 + c0 + tx];
  }
  __syncthreads();
  #pragma unroll
  for (int i = 0; i < 4; ++i) {
    int c = c0 + ty + i * 8;
    int p = p0 + tx;
    if (p < NPOS) out[(size_t)c * NPOS + p] = t[tx][ty + i * 8];
  }
}

// ---------------- im2col for 3x3 SAME conv on feat_cyx ----------------
__global__ __launch_bounds__(256) void k_imcol(const float* __restrict__ fcyx, float* __restrict__ im) {
  int idx = blockIdx.x * 256 + threadIdx.x;   // quad index
  if (idx >= NPOS * 1152) return;
  int p = idx / 1152, q = idx - p * 1152;
  int y = p / FW, x = p - y * FW;
  float4 v;
  #pragma unroll
  for (int j = 0; j < 4; ++j) {
    int k = q * 4 + j;
    int ci = k / 9, r = k - ci * 9, ky = r / 3, kx = r - ky * 3;
    int yy = y + ky - 1, xx = x + kx - 1;
    float val = 0.f;
    if (yy >= 0 && yy < FH && xx >= 0 && xx < FW) val = fcyx[(size_t)ci * NPOS + yy * FW + xx];
    ((float*)&v)[j] = val;
  }
  *(float4*)&im[(size_t)idx * 4] = v;
}

// ---------------- merged RPN 1x1 convs: layer1[NPOS][512] x (Wloc||Wsc) ----------------
__global__ __launch_bounds__(256) void k_gemm_rpn(
    const float* __restrict__ A, const float* __restrict__ Wloc, const float* __restrict__ Wsc,
    const float* __restrict__ bloc, const float* __restrict__ bsc,
    float* __restrict__ rpnloc, float* __restrict__ rpnsc)
{
  __shared__ float As[16][68];
  __shared__ float Bs[16][68];
  int tid = threadIdx.x;
  int bm = blockIdx.x * 64;
  int tx = tid & 15, ty = tid >> 4;
  float acc[4][4] = {};
  int lr = tid >> 2, lk = (tid & 3) * 4;
  int ar = bm + lr; if (ar >= NPOS) ar = NPOS - 1;
  const float* ap = A + (size_t)ar * 512 + lk;
  const float* bp;
  if (lr < 36)      bp = Wloc + (size_t)lr * 512 + lk;
  else if (lr < 54) bp = Wsc + (size_t)(lr - 36) * 512 + lk;
  else              bp = Wsc + lk;   // dummy row, output discarded
  for (int k0 = 0; k0 < 512; k0 += 16) {
    float4 av = *(const float4*)(ap + k0);
    float4 bv = *(const float4*)(bp + k0);
    As[lk + 0][lr] = av.x; As[lk + 1][lr] = av.y; As[lk + 2][lr] = av.z; As[lk + 3][lr] = av.w;
    Bs[lk + 0][lr] = bv.x; Bs[lk + 1][lr] = bv.y; Bs[lk + 2][lr] = bv.z; Bs[lk + 3][lr] = bv.w;
    __syncthreads();
    #pragma unroll
    for (int k = 0; k < 16; ++k) {
      float4 a = *(const float4*)&As[k][ty * 4];
      float4 b = *(const float4*)&Bs[k][tx * 4];
      acc[0][0] += a.x * b.x; acc[0][1] += a.x * b.y; acc[0][2] += a.x * b.z; acc[0][3] += a.x * b.w;
      acc[1][0] += a.y * b.x; acc[1][1] += a.y * b.y; acc[1][2] += a.y * b.z; acc[1][3] += a.y * b.w;
      acc[2][0] += a.z * b.x; acc[2][1] += a.z * b.y; acc[2][2] += a.z * b.z; acc[2][3] += a.z * b.w;
      acc[3][0] += a.w * b.x; acc[3][1] += a.w * b.y; acc[3][2] += a.w * b.z; acc[3][3] += a.w * b.w;
    }
    __syncthreads();
  }
  #pragma unroll
  for (int i = 0; i < 4; ++i) {
    int m = bm + ty * 4 + i;
    if (m >= NPOS) continue;
    #pragma unroll
    for (int j = 0; j < 4; ++j) {
      int n = tx * 4 + j;
      if (n < 36)      rpnloc[(size_t)m * 36 + n] = acc[i][j] + bloc[n];
      else if (n < 54) rpnsc[(size_t)m * 18 + (n - 36)] = acc[i][j] + bsc[n - 36];
    }
  }
}

// ---------------- proposals: decode boxes, clip, validity, sort keys ----------------
__global__ __launch_bounds__(256) void k_proposal(
    const float* __restrict__ rpnloc, const float* __restrict__ rpnsc,
    const void* __restrict__ scalep, float4* __restrict__ roi_all,
    unsigned long long* __restrict__ keys)
{
  int a = blockIdx.x * 256 + threadIdx.x;
  if (a >= NANCH) return;
  int s = a / 9, t = a - s * 9;
  int iy = s / FW, ix = s - iy * FW;
  float sy = iy * 16.f, sx = ix * 16.f;
  float ay1 = c_AB[t][0] + sy, ax1 = c_AB[t][1] + sx;
  float ay2 = c_AB[t][2] + sy, ax2 = c_AB[t][3] + sx;
  const float* lp = rpnloc + (size_t)s * 36 + t * 4;
  float dy = lp[0], dx = lp[1], dh = lp[2], dw = lp[3];
  float ph = ay2 - ay1, pw = ax2 - ax1;
  float py = ay1 + 0.5f * ph, px = ax1 + 0.5f * pw;
  float cy = dy * ph + py, cx = dx * pw + px;
  float hh = expf(dh) * ph, ww = expf(dw) * pw;
  float y1 = cy - 0.5f * hh, x1 = cx - 0.5f * ww;
  float y2 = cy + 0.5f * hh, x2 = cx + 0.5f * ww;
  y1 = fminf(fmaxf(y1, 0.f), (float)HIMG); y2 = fminf(fmaxf(y2, 0.f), (float)HIMG);
  x1 = fminf(fmaxf(x1, 0.f), (float)WIMG); x2 = fminf(fmaxf(x2, 0.f), (float)WIMG);
  int iv = *(const int*)scalep;
  float scale = (iv >= 1 && iv < 1000000) ? (float)iv : *(const float*)scalep;
  float minsz = 16.f * scale;
  bool valid = (y2 - y1 >= minsz) && (x2 - x1 >= minsz);
  float fg = rpnsc[(size_t)s * 18 + t * 2 + 1];
  float sc = valid ? fg : __uint_as_float(0xFF800000u);   // -inf
  unsigned u = __float_as_uint(sc);
  u = (u & 0x80000000u) ? ~u : (u | 0x80000000u);         // order-preserving uint
  keys[a] = (((unsigned long long)(~u)) << 32) | (unsigned)a;  // asc sort == desc score, ties by idx
  roi_all[a] = make_float4(y1, x1, y2, x2);
}

// ---------------- single-block top-2000: radix select + LDS bitonic ----------------
__global__ __launch_bounds__(1024) void k_topk(
    const unsigned long long* __restrict__ keys, const float4* __restrict__ roi_all,
    float4* __restrict__ boxes, int* __restrict__ vbs)
{
  __shared__ unsigned int hist[256];
  __shared__ unsigned long long prefix;
  __shared__ int rankr;
  __shared__ int cnt;
  __shared__ unsigned long long sk[2048];
  int tid = threadIdx.x;
  if (tid == 0) { prefix = 0ULL; rankr = PRE - 1; }
  __syncthreads();
  for (int p = 7; p >= 0; --p) {
    if (tid < 256) hist[tid] = 0;
    __syncthreads();
    unsigned long long pref = prefix;
    int shift = (p + 1) * 8;
    for (int i = tid; i < NANCH; i += 1024) {
      unsigned long long k = keys[i];
      bool match = (p == 7) || ((k >> shift) == (pref >> shift));
      if (match) atomicAdd(&hist[(unsigned)(k >> (p * 8)) & 255u], 1u);
    }
    __syncthreads();
    if (tid == 0) {
      int r = rankr;
      unsigned cum = 0;
      for (int b2 = 0; b2 < 256; ++b2) {
        unsigned c = hist[b2];
        if (cum + c > (unsigned)r) { prefix |= ((unsigned long long)b2) << (p * 8); rankr = r - (int)cum; break; }
        cum += c;
      }
    }
    __syncthreads();
  }
  unsigned long long kth = prefix;
  if (tid == 0) cnt = 0;
  __syncthreads();
  for (int i = tid; i < NANCH; i += 1024) {
    unsigned long long k = keys[i];
    if (k <= kth) {
      int pos = atomicAdd(&cnt, 1);
      if (pos < 2048) sk[pos] = k;
    }
  }
  __syncthreads();
  if (tid < 48) sk[2000 + tid] = ~0ULL;
  __syncthreads();
  for (int size = 2; size <= 2048; size <<= 1) {
    for (int stride = size >> 1; stride > 0; stride >>= 1) {
      int i = 2 * tid - (tid & (stride - 1));
      int j = i + stride;
      unsigned long long a = sk[i], b = sk[j];
      bool asc = ((i & size) == 0);
      bool sw = asc ? (a > b) : (a < b);
      __syncthreads();
      if (sw) { sk[i] = b; sk[j] = a; }
      __syncthreads();
    }
  }
  for (int i = tid; i < PRE; i += 1024) {
    unsigned long long k = sk[i];
    int a = (int)(k & 0xFFFFFFFFULL);
    boxes[i] = roi_all[a];
    vbs[i] = ((unsigned)(k >> 32) < 0xFF800000u) ? 1 : 0;
  }
}

// ---------------- suppression bitmask ----------------
__global__ __launch_bounds__(64) void k_supmat(const float4* __restrict__ boxes,
                                               unsigned long long* __restrict__ supmat)
{
  int i = blockIdx.x;
  int lane = threadIdx.x;
  float4 bi = boxes[i];
  float ai = (bi.z - bi.x + 1.f) * (bi.w - bi.y + 1.f);
  for (int w = 0; w < 32; ++w) {
    int j = w * 64 + lane;
    bool sup = false;
    if (j < PRE && j > i) {
      float4 bj = boxes[j];
      float aj = (bj.z - bj.x + 1.f) * (bj.w - bj.y + 1.f);
      float iy1 = fmaxf(bi.x, bj.x), ix1 = fmaxf(bi.y, bj.y);
      float iy2 = fminf(bi.z, bj.z), ix2 = fminf(bi.w, bj.w);
      float ih = fmaxf(iy2 - iy1 + 1.f, 0.f), iw = fmaxf(ix2 - ix1 + 1.f, 0.f);
      float inter = ih * iw;
      float iou = inter / (ai + aj - inter);
      sup = iou > 0.7f;
    }
    unsigned long long word = __ballot(sup);
    if (lane == 0) supmat[(size_t)i * 32 + w] = word;
  }
}

// ---------------- sequential NMS scan + kept-first selection + rois write ----------------
__global__ __launch_bounds__(256) void k_nms(
    const unsigned long long* __restrict__ supmat, const int* __restrict__ vbs,
    const float4* __restrict__ boxes, float* __restrict__ rois_ws, float* __restrict__ out_rois)
{
  __shared__ unsigned long long rows[64][32];
  __shared__ unsigned long long removed[32];
  __shared__ unsigned long long keepw[32];
  __shared__ unsigned long long kmsh;
  __shared__ int pref[33];
  __shared__ int sel[2048];
  int tid = threadIdx.x;
  if (tid < 32) removed[tid] = 0ULL;
  __syncthreads();
  for (int b = 0; b < 32; ++b) {
    for (int t = tid; t < 2048; t += 256) {
      int k = t >> 5, w = t & 31;
      rows[k][w] = supmat[(size_t)(b * 64 + k) * 32 + w];
    }
    __syncthreads();
    if (tid < 64) {
      int lane = tid;
      int gj = b * 64 + lane;
      int vb = (gj < PRE) ? vbs[gj] : 0;
      unsigned long long vbw = __ballot(vb != 0);
      unsigned long long km = vbw & ~removed[b];
      unsigned long long Wj = rows[lane][b];
      for (int k = 0; k < 64; ++k) {
        unsigned long long wk = __shfl(Wj, k);
        if ((km >> k) & 1ULL) km &= ~wk;
      }
      if (lane == 0) { keepw[b] = km; kmsh = km; }
    }
    __syncthreads();
    {
      unsigned long long km = kmsh;
      int w = tid & 31, kb = (tid >> 5) * 8;
      unsigned long long acc = 0ULL;
      for (int k = kb; k < kb + 8; ++k)
        if ((km >> k) & 1ULL) acc |= rows[k][w];
      if (acc) atomicOr((unsigned long long*)&removed[w], acc);
    }
    __syncthreads();
  }
  if (tid == 0) {
    pref[0] = 0;
    for (int w = 0; w < 32; ++w) pref[w + 1] = pref[w] + __popcll(keepw[w]);
  }
  __syncthreads();
  if (tid < 32) {
    int w = tid;
    unsigned long long bits = keepw[w];
    int base = pref[w], r = 0;
    for (int bit = 0; bit < 64; ++bit)
      if ((bits >> bit) & 1ULL) { sel[base + r] = w * 64 + bit; r++; }
    int Kc = pref[32];
    unsigned long long mask = (w < 31) ? ~0ULL : 0xFFFFULL;     // 2000 = 31*64+16
    unsigned long long ub = ~keepw[w] & mask;
    int ubase = Kc + (w * 64 - pref[w]); r = 0;
    for (int bit = 0; bit < 64; ++bit)
      if ((ub >> bit) & 1ULL) { sel[ubase + r] = w * 64 + bit; r++; }
  }
  __syncthreads();
  for (int t = tid; t < POST; t += 256) {
    float4 bx = boxes[sel[t]];
    rois_ws[t * 4 + 0] = bx.x; rois_ws[t * 4 + 1] = bx.y;
    rois_ws[t * 4 + 2] = bx.z; rois_ws[t * 4 + 3] = bx.w;
    out_rois[t * 4 + 0] = bx.x; out_rois[t * 4 + 1] = bx.y;
    out_rois[t * 4 + 2] = bx.z; out_rois[t * 4 + 3] = bx.w;
  }
}

// ---------------- ROI adaptive max-pool 7x7 -> pool bf16 [300][512*49] ----------------
__global__ __launch_bounds__(256) void k_roipool(
    const float* __restrict__ feat_yxc, const float* __restrict__ rois,
    unsigned short* __restrict__ poolbf)
{
  int r = blockIdx.x, cg = blockIdx.y;
  int lane = threadIdx.x & 63, bslot = threadIdx.x >> 6;
  int c = cg * 64 + lane;
  float b0 = rois[r * 4 + 0], b1 = rois[r * 4 + 1], b2 = rois[r * 4 + 2], b3 = rois[r * 4 + 3];
  int y0 = min(max((int)floorf(b0 * 0.0625f), 0), FH - 1);
  int x0 = min(max((int)floorf(b1 * 0.0625f), 0), FW - 1);
  int y1 = min(max((int)floorf(b2 * 0.0625f), 0), FH - 1);
  int x1 = min(max((int)floorf(b3 * 0.0625f), 0), FW - 1);
  int Hh = y1 - y0 + 1, Ww = x1 - x0 + 1;
  for (int bin = bslot; bin < 49; bin += 4) {
    int by = bin / 7, bx = bin - by * 7;
    int rs = y0 + (by * Hh) / 7, re = y0 + ((by + 1) * Hh + 6) / 7;
    int cs = x0 + (bx * Ww) / 7, ce = x0 + ((bx + 1) * Ww + 6) / 7;
    float m = -1e30f;
    for (int y = rs; y < re; ++y)
      for (int x = cs; x < ce; ++x)
        m = fmaxf(m, feat_yxc[((size_t)(y * FW + x)) * 512 + c]);
    poolbf[(size_t)r * 25088 + c * 49 + bin] = f2bf(m);
  }
}

// ---------------- FC/heads bf16 MFMA GEMM, split-K, BM=160 x BN=128 ----------------
template<bool BBF16>
__global__ __launch_bounds__(512) void k_fcg(
    const unsigned short* __restrict__ A, const void* __restrict__ Bv,
    float* __restrict__ P, int K, int N)
{
  __shared__ unsigned short As[160 * 40];
  __shared__ unsigned short Bs[128 * 40];
  int tid = threadIdx.x;
  int bn = blockIdx.x * 128;
  int bm = blockIdx.y * 160;
  int sk2 = blockIdx.z;
  int KC = K >> 3;
  int k0beg = sk2 * KC, kend = k0beg + KC;
  int w = tid >> 6, lane = tid & 63;
  int wm = w >> 2, wn = w & 3;
  int l15 = lane & 15, lg = lane >> 4;
  int arow0 = tid >> 2, aq0 = tid & 3;
  int arow1 = 128 + (tid >> 2);
  int kr = tid >> 4, bm_ = tid & 15, nn = bm_ * 8;
  int bpos = (((kr >> 3) ^ (bm_ & 3)) << 3) | (kr & 7);
  const float* Bf = (const float*)Bv;
  const unsigned short* Bh = (const unsigned short*)Bv;

  f32x4 acc[5][2];
  #pragma unroll
  for (int a_ = 0; a_ < 5; ++a_) {
    acc[a_][0] = (f32x4){0.f, 0.f, 0.f, 0.f};
    acc[a_][1] = (f32x4){0.f, 0.f, 0.f, 0.f};
  }

  uint4 ra0, ra1, rbh;
  float4 rb0, rb1;
  ra0 = *(const uint4*)(A + (size_t)(bm + arow0) * K + k0beg + aq0 * 8);
  if (tid < 128) ra1 = *(const uint4*)(A + (size_t)(bm + arow1) * K + k0beg + aq0 * 8);
  if (BBF16) rbh = *(const uint4*)(Bh + (size_t)(k0beg + kr) * N + bn + nn);
  else {
    rb0 = *(const float4*)(Bf + (size_t)(k0beg + kr) * N + bn + nn);
    rb1 = *(const float4*)(Bf + (size_t)(k0beg + kr) * N + bn + nn + 4);
  }

  for (int k0 = k0beg; k0 < kend; k0 += 32) {
    *(uint4*)(&As[arow0 * 40 + aq0 * 8]) = ra0;
    if (tid < 128) *(uint4*)(&As[arow1 * 40 + aq0 * 8]) = ra1;
    {
      unsigned short bb[8];
      if (BBF16) {
        const unsigned short* pp = (const unsigned short*)&rbh;
        #pragma unroll
        for (int j = 0; j < 8; ++j) bb[j] = pp[j];
      } else {
        bb[0] = f2bf(rb0.x); bb[1] = f2bf(rb0.y); bb[2] = f2bf(rb0.z); bb[3] = f2bf(rb0.w);
        bb[4] = f2bf(rb1.x); bb[5] = f2bf(rb1.y); bb[6] = f2bf(rb1.z); bb[7] = f2bf(rb1.w);
      }
      #pragma unroll
      for (int j = 0; j < 8; ++j) Bs[(nn + j) * 40 + bpos] = bb[j];
    }
    __syncthreads();
    if (k0 + 32 < kend) {
      ra0 = *(const uint4*)(A + (size_t)(bm + arow0) * K + k0 + 32 + aq0 * 8);
      if (tid < 128) ra1 = *(const uint4*)(A + (size_t)(bm + arow1) * K + k0 + 32 + aq0 * 8);
      if (BBF16) rbh = *(const uint4*)(Bh + (size_t)(k0 + 32 + kr) * N + bn + nn);
      else {
        rb0 = *(const float4*)(Bf + (size_t)(k0 + 32 + kr) * N + bn + nn);
        rb1 = *(const float4*)(Bf + (size_t)(k0 + 32 + kr) * N + bn + nn + 4);
      }
    }
    bf16x8 bf[2];
    #pragma unroll
    for (int ns = 0; ns < 2; ++ns) {
      int n = wn * 32 + ns * 16 + l15;
      int g = lg ^ ((n >> 3) & 3);
      bf[ns] = *(const bf16x8*)(&Bs[n * 40 + g * 8]);
    }
    #pragma unroll
    for (int mt = 0; mt < 5; ++mt) {
      int row = wm * 80 + mt * 16 + l15;
      bf16x8 af = *(const bf16x8*)(&As[row * 40 + lg * 8]);
      acc[mt][0] = __builtin_amdgcn_mfma_f32_16x16x32_bf16(af, bf[0], acc[mt][0], 0, 0, 0);
      acc[mt][1] = __builtin_amdgcn_mfma_f32_16x16x32_bf16(af, bf[1], acc[mt][1], 0, 0, 0);
    }
    __syncthreads();
  }
  float* Pp = P + (size_t)sk2 * 320 * N;
  #pragma unroll
  for (int mt = 0; mt < 5; ++mt)
    #pragma unroll
    for (int ns = 0; ns < 2; ++ns)
      #pragma unroll
      for (int r2 = 0; r2 < 4; ++r2) {
        int m = bm + wm * 80 + mt * 16 + lg * 4 + r2;
        int n = bn + wn * 32 + ns * 16 + l15;
        Pp[(size_t)m * N + n] = acc[mt][ns][r2];
      }
}

// ---------------- pack Wl||Ws -> bf16 [4096][128] ----------------
__global__ __launch_bounds__(256) void k_wpack(
    const float* __restrict__ Wl, const float* __restrict__ Wsv, unsigned short* __restrict__ Wcat)
{
  int idx = blockIdx.x * 256 + threadIdx.x;
  if (idx >= 4096 * 128) return;
  int k = idx >> 7, n = idx & 127;
  float v = 0.f;
  if (n < 84) v = Wl[(size_t)k * 84 + n];
  else if (n < 105) v = Wsv[(size_t)k * 21 + (n - 84)];
  Wcat[idx] = f2bf(v);
}

// ---------------- heads reduce: sum 8 partials + bias -> out ----------------
__global__ __launch_bounds__(256) void k_headreduce(
    const float* __restrict__ P, const float* __restrict__ bl, const float* __restrict__ bs,
    float* __restrict__ out)
{
  int idx = blockIdx.x * 256 + threadIdx.x;
  if (idx >= 300 * 105) return;
  int m = idx / 105, n = idx - m * 105;
  float s = 0.f;
  #pragma unroll
  for (int s2 = 0; s2 < 8; ++s2) s += P[(size_t)s2 * 320 * 128 + m * 128 + n];
  if (n < 84) out[(size_t)m * 84 + n] = s + bl[n];
  else        out[25200 + (size_t)m * 21 + (n - 84)] = s + bs[n - 84];
}

// ---------------- reduce split-K partials ----------------
__global__ __launch_bounds__(256) void k_reduce1(
    const float* __restrict__ P, const float* __restrict__ b1, unsigned short* __restrict__ h1bf)
{
  int idx = blockIdx.x * 256 + threadIdx.x;
  if (idx >= 320 * 4096) return;
  int m = idx >> 12, n = idx & 4095;
  float s = b1[n];
  #pragma unroll
  for (int s2 = 0; s2 < 8; ++s2) s += P[(size_t)s2 * 320 * 4096 + idx];
  s = fmaxf(s, 0.f);
  h1bf[idx] = (m < 300) ? f2bf(s) : (unsigned short)0;
}

__global__ __launch_bounds__(256) void k_reduce2(
    const float* __restrict__ P, const float* __restrict__ b2, unsigned short* __restrict__ fc7bf)
{
  int idx = blockIdx.x * 256 + threadIdx.x;
  if (idx >= 300 * 4096) return;
  int n = idx & 4095;
  float s = b2[n];
  #pragma unroll
  for (int s2 = 0; s2 < 8; ++s2) s += P[(size_t)s2 * 320 * 4096 + idx];
  fc7bf[idx] = f2bf(fmaxf(s, 0.f));
}

// ===========================================================================
extern "C" void kernel_launch(void* const* d_in, const int* in_sizes, int n_in,
                              void* d_out, int out_size, void* d_ws, size_t ws_size,
                              hipStream_t stream)
{
  const float* x    = (const float*)d_in[0];
  const float* Wext = (const float*)d_in[1];
  const float* Wc1  = (const float*)d_in[2];
  const float* bc1  = (const float*)d_in[3];
  const float* Wloc = (const float*)d_in[4];
  const float* bloc = (const float*)d_in[5];
  const float* Wsc  = (const float*)d_in[6];
  const float* bsc  = (const float*)d_in[7];
  const float* W1   = (const float*)d_in[8];
  const float* b1   = (const float*)d_in[9];
  const float* W2   = (const float*)d_in[10];
  const float* b2   = (const float*)d_in[11];
  const float* Wl   = (const float*)d_in[12];
  const float* bl   = (const float*)d_in[13];
  const float* Wsv  = (const float*)d_in[14];
  const float* bs   = (const float*)d_in[15];
  const void*  scalep = d_in[16];
  float* out = (float*)d_out;
  char* ws = (char*)d_ws;

  // All regions dedicated (no aliasing; ws_size ~1.6 GB, usage ~176 MB).
  size_t off = 0;
  auto alloc = [&](size_t b) { size_t o = off; off += (b + 255) & ~(size_t)255; return o; };
  size_t o_featyxc = alloc((size_t)NPOS * 512 * 4);
  size_t o_featcyx = alloc((size_t)512 * NPOS * 4);
  size_t o_layer1  = alloc((size_t)NPOS * 512 * 4);
  size_t o_rpnloc  = alloc((size_t)NPOS * 36 * 4);
  size_t o_rpnsc   = alloc((size_t)NPOS * 18 * 4);
  size_t o_roiall  = alloc((size_t)NANCH * 16);
  size_t o_keys    = alloc((size_t)NANCH * 8);
  size_t o_boxes   = alloc((size_t)PRE * 16);
  size_t o_vbs     = alloc((size_t)PRE * 4);
  size_t o_supmat  = alloc((size_t)PRE * 32 * 8);
  size_t o_rois    = alloc((size_t)POST * 16);
  size_t o_poolbf  = alloc((size_t)320 * 25088 * 2);
  size_t o_h1bf    = alloc((size_t)320 * 4096 * 2);
  size_t o_wcat    = alloc((size_t)4096 * 128 * 2);
  size_t o_imx     = alloc((size_t)NPOS * 4608 * 4);
  size_t o_cpart   = alloc((size_t)8 * NPOS * 512 * 4);
  size_t o_part    = alloc((size_t)8 * 320 * 4096 * 4);
  (void)ws_size; (void)in_sizes; (void)n_in; (void)out_size;

  float* feat_yxc = (float*)(ws + o_featyxc);
  float* feat_cyx = (float*)(ws + o_featcyx);
  float* layer1   = (float*)(ws + o_layer1);
  float* rpnloc   = (float*)(ws + o_rpnloc);
  float* rpnsc    = (float*)(ws + o_rpnsc);
  float4* roi_all = (float4*)(ws + o_roiall);
  unsigned long long* keys = (unsigned long long*)(ws + o_keys);
  float4* boxes   = (float4*)(ws + o_boxes);
  int* vbs        = (int*)(ws + o_vbs);
  unsigned long long* supmat = (unsigned long long*)(ws + o_supmat);
  float* rois     = (float*)(ws + o_rois);
  unsigned short* poolbf = (unsigned short*)(ws + o_poolbf);
  unsigned short* h1bf   = (unsigned short*)(ws + o_h1bf);
  unsigned short* wcat   = (unsigned short*)(ws + o_wcat);
  float* imx      = (float*)(ws + o_imx);
  float* cpart    = (float*)(ws + o_cpart);
  float* partials = (float*)(ws + o_part);

  // pack head weights (independent)
  k_wpack<<<(4096 * 128) / 256, 256, 0, stream>>>(Wl, Wsv, wcat);
  // feature extractor (16x16 stride-16 patch conv) + relu  [8x8 tile, split-K=4]
  k_imext<<<(NPOS * 768) / 256, 256, 0, stream>>>(x, imx);
  k_gemm_sk8<<<dim3(19, 4, 4), 256, 0, stream>>>(imx, Wext, cpart, NPOS, 768, 192);
  k_reduce_conv<false, 4><<<(NPOS * 128 + 255) / 256, 256, 0, stream>>>(cpart, nullptr, feat_yxc, NPOS);
  k_transpose<<<dim3(75, 16), 256, 0, stream>>>(feat_yxc, feat_cyx);
  // 3x3 conv 512->512 SAME + bias + relu (fp32 for score exactness) [8x8 tile, split-K=8]
  k_imcol<<<(NPOS * 1152) / 256, 256, 0, stream>>>(feat_cyx, imx);
  k_gemm_sk8<<<dim3(19, 4, 8), 256, 0, stream>>>(imx, Wc1, cpart, NPOS, 4608, 576);
  k_reduce_conv<true, 8><<<(NPOS * 128 + 255) / 256, 256, 0, stream>>>(cpart, bc1, layer1, NPOS);
  // merged RPN 1x1 convs (fp32, identical accumulation order to the split pair)
  k_gemm_rpn<<<38, 256, 0, stream>>>(layer1, Wloc, Wsc, bloc, bsc, rpnloc, rpnsc);
  // proposals -> top-2000 -> NMS -> rois
  k_proposal<<<(NANCH + 255) / 256, 256, 0, stream>>>(rpnloc, rpnsc, scalep, roi_all, keys);
  k_topk<<<1, 1024, 0, stream>>>(keys, roi_all, boxes, vbs);
  k_supmat<<<PRE, 64, 0, stream>>>(boxes, supmat);
  k_nms<<<1, 256, 0, stream>>>(supmat, vbs, boxes, rois, out + 31500);
  // ROI max-pool -> bf16 pool rows 0..299 (rows 300..319 discarded by reduce1)
  k_roipool<<<dim3(POST, 8), 256, 0, stream>>>(feat_yxc, rois, poolbf);
  // FC1 -> relu -> FC2 -> relu -> heads (bf16 MFMA, split-K=8)
  k_fcg<false><<<dim3(32, 2, 8), 512, 0, stream>>>(poolbf, W1, partials, 25088, 4096);
  k_reduce1<<<(320 * 4096) / 256, 256, 0, stream>>>(partials, b1, h1bf);
  k_fcg<false><<<dim3(32, 2, 8), 512, 0, stream>>>(h1bf, W2, partials, 4096, 4096);
  k_reduce2<<<(300 * 4096) / 256, 256, 0, stream>>>(partials, b2, h1bf);
  k_fcg<true><<<dim3(1, 2, 8), 512, 0, stream>>>(h1bf, wcat, partials, 4096, 128);
  k_headreduce<<<(300 * 105 + 255) / 256, 256, 0, stream>>>(partials, bl, bs, out);
}

// Round 9
// 844.954 us; speedup vs baseline: 8.9337x; 8.9337x over previous
//
#include <hip/hip_runtime.h>
#include <stdint.h>

#define FH 38
#define FW 63
#define NPOS 2394           // 38*63
#define NANCH 21546         // NPOS*9
#define HIMG 608
#define WIMG 1008
#define PRE 2000
#define POST 300

typedef __attribute__((ext_vector_type(8))) short bf16x8;
typedef __attribute__((ext_vector_type(4))) float f32x4;

__device__ __constant__ float c_AB[9][4] = {
  {-37.254833f,-82.50967f,53.254833f,98.50967f},
  {-82.50967f,-173.01933f,98.50967f,189.01933f},
  {-173.01933f,-354.03867f,189.01933f,370.03867f},
  {-56.f,-56.f,72.f,72.f},
  {-120.f,-120.f,136.f,136.f},
  {-248.f,-248.f,264.f,264.f},
  {-82.50967f,-37.254833f,98.50967f,53.254833f},
  {-173.01933f,-82.50967f,189.01933f,98.50967f},
  {-354.03867f,-173.01933f,370.03867f,189.01933f}};

__device__ __forceinline__ unsigned short f2bf(float f) {
  unsigned u = __float_as_uint(f);
  u += 0x7FFFu + ((u >> 16) & 1u);
  return (unsigned short)(u >> 16);
}

// ---------------- im2col for the 16x16 stride-16 extractor ----------------
__global__ __launch_bounds__(256) void k_imext(const float* __restrict__ x, float* __restrict__ im) {
  int idx = blockIdx.x * 256 + threadIdx.x;
  if (idx >= NPOS * 768) return;
  int p = idx / 768, k = idx - p * 768;
  int ci = k >> 8, r = k & 255, ky = r >> 4, kx = r & 15;
  int py = p / FW, px = p - py * FW;
  im[idx] = x[((size_t)ci * HIMG + py * 16 + ky) * WIMG + px * 16 + kx];
}

// ---------------- split-K fp32 GEMM: A[M][K] * B[512][K]^T -> P[s][M][512] ----------------
// BM=128, BN=64, 256 threads, 8x4 per thread, BK=16. Proven R5/R7 kernel (VGPR ~84,
// no spill). 8x8-tile variants failed twice: R6 fused-im2col -> 256 VGPR; R8
// __launch_bounds__(256,4) -> allocator squeezed to 64 VGPR, acc spilled to scratch
// (17 GB HBM traffic, 6 ms). Do not revisit without a compile-time resource check.
__global__ __launch_bounds__(256) void k_gemm_sk(
    const float* __restrict__ A, const float* __restrict__ B,
    float* __restrict__ P, int M, int K, int Kc)
{
  __shared__ float As[16][132];
  __shared__ float Bs[16][68];
  int tid = threadIdx.x;
  int bm = blockIdx.x * 128, bn = blockIdx.y * 64;
  int k0 = blockIdx.z * Kc;
  int kend = k0 + Kc;
  int tx = tid & 15, ty = tid >> 4;
  float4 acc[8];
  #pragma unroll
  for (int i = 0; i < 8; ++i) acc[i] = make_float4(0.f, 0.f, 0.f, 0.f);
  int lr = tid >> 2, lk = (tid & 3) * 4;
  int ar0 = bm + lr;      if (ar0 >= M) ar0 = M - 1;
  int ar1 = bm + lr + 64; if (ar1 >= M) ar1 = M - 1;
  const float* ap0 = A + (size_t)ar0 * K + lk;
  const float* ap1 = A + (size_t)ar1 * K + lk;
  const float* bp  = B + (size_t)(bn + lr) * K + lk;
  float4 ra0 = *(const float4*)(ap0 + k0);
  float4 ra1 = *(const float4*)(ap1 + k0);
  float4 rb  = *(const float4*)(bp  + k0);
  for (; k0 < kend; k0 += 16) {
    As[lk + 0][lr] = ra0.x; As[lk + 1][lr] = ra0.y; As[lk + 2][lr] = ra0.z; As[lk + 3][lr] = ra0.w;
    As[lk + 0][lr + 64] = ra1.x; As[lk + 1][lr + 64] = ra1.y; As[lk + 2][lr + 64] = ra1.z; As[lk + 3][lr + 64] = ra1.w;
    Bs[lk + 0][lr] = rb.x; Bs[lk + 1][lr] = rb.y; Bs[lk + 2][lr] = rb.z; Bs[lk + 3][lr] = rb.w;
    __syncthreads();
    if (k0 + 16 < kend) {
      ra0 = *(const float4*)(ap0 + k0 + 16);
      ra1 = *(const float4*)(ap1 + k0 + 16);
      rb  = *(const float4*)(bp  + k0 + 16);
    }
    #pragma unroll
    for (int k = 0; k < 16; ++k) {
      float4 aL = *(const float4*)&As[k][ty * 8];
      float4 aH = *(const float4*)&As[k][ty * 8 + 4];
      float4 b  = *(const float4*)&Bs[k][tx * 4];
      float av0 = aL.x, av1 = aL.y, av2 = aL.z, av3 = aL.w;
      float av4 = aH.x, av5 = aH.y, av6 = aH.z, av7 = aH.w;
      acc[0].x += av0 * b.x; acc[0].y += av0 * b.y; acc[0].z += av0 * b.z; acc[0].w += av0 * b.w;
      acc[1].x += av1 * b.x; acc[1].y += av1 * b.y; acc[1].z += av1 * b.z; acc[1].w += av1 * b.w;
      acc[2].x += av2 * b.x; acc[2].y += av2 * b.y; acc[2].z += av2 * b.z; acc[2].w += av2 * b.w;
      acc[3].x += av3 * b.x; acc[3].y += av3 * b.y; acc[3].z += av3 * b.z; acc[3].w += av3 * b.w;
      acc[4].x += av4 * b.x; acc[4].y += av4 * b.y; acc[4].z += av4 * b.z; acc[4].w += av4 * b.w;
      acc[5].x += av5 * b.x; acc[5].y += av5 * b.y; acc[5].z += av5 * b.z; acc[5].w += av5 * b.w;
      acc[6].x += av6 * b.x; acc[6].y += av6 * b.y; acc[6].z += av6 * b.z; acc[6].w += av6 * b.w;
      acc[7].x += av7 * b.x; acc[7].y += av7 * b.y; acc[7].z += av7 * b.z; acc[7].w += av7 * b.w;
    }
    __syncthreads();
  }
  float* Pp = P + (size_t)blockIdx.z * M * 512;
  #pragma unroll
  for (int i = 0; i < 8; ++i) {
    int m = bm + ty * 8 + i;
    if (m < M) *(float4*)&Pp[(size_t)m * 512 + bn + tx * 4] = acc[i];
  }
}

// ---------------- reduce split-K conv partials (+bias, relu) ----------------
template<bool BIAS>
__global__ __launch_bounds__(256) void k_reduce_conv(
    const float* __restrict__ P, const float* __restrict__ bias,
    float* __restrict__ C, int M)
{
  int i = blockIdx.x * 256 + threadIdx.x;      // float4 index
  int total = M * 128;                          // M*512/4
  if (i >= total) return;
  size_t stride = (size_t)M * 512;
  float4 s = make_float4(0.f, 0.f, 0.f, 0.f);
  if (BIAS) s = *(const float4*)&bias[(i * 4) & 511];
  #pragma unroll
  for (int s2 = 0; s2 < 4; ++s2) {
    float4 v = *(const float4*)&P[s2 * stride + (size_t)i * 4];
    s.x += v.x; s.y += v.y; s.z += v.z; s.w += v.w;
  }
  s.x = fmaxf(s.x, 0.f); s.y = fmaxf(s.y, 0.f); s.z = fmaxf(s.z, 0.f); s.w = fmaxf(s.w, 0.f);
  *(float4*)&C[(size_t)i * 4] = s;
}

// ---------------- transpose [NPOS][512] -> [512][NPOS] ----------------
__global__ __launch_bounds__(256) void k_transpose(const float* __restrict__ in, float* __restrict__ out) {
  __shared__ float t[32][33];
  int tx = threadIdx.x & 31, ty = threadIdx.x >> 5;
  int p0 = blockIdx.x * 32, c0 = blockIdx.y * 32;
  #pragma unroll
  for (int i = 0; i < 4; ++i) {
    int p = p0 + ty + i * 8;
    if (p < NPOS) t[ty + i * 8][tx] = in[(size_t)p * 512 + c0 + tx];
  }
  __syncthreads();
  #pragma unroll
  for (int i = 0; i < 4; ++i) {
    int c = c0 + ty + i * 8;
    int p = p0 + tx;
    if (p < NPOS) out[(size_t)c * NPOS + p] = t[tx][ty + i * 8];
  }
}

// ---------------- im2col for 3x3 SAME conv on feat_cyx ----------------
__global__ __launch_bounds__(256) void k_imcol(const float* __restrict__ fcyx, float* __restrict__ im) {
  int idx = blockIdx.x * 256 + threadIdx.x;   // quad index
  if (idx >= NPOS * 1152) return;
  int p = idx / 1152, q = idx - p * 1152;
  int y = p / FW, x = p - y * FW;
  float4 v;
  #pragma unroll
  for (int j = 0; j < 4; ++j) {
    int k = q * 4 + j;
    int ci = k / 9, r = k - ci * 9, ky = r / 3, kx = r - ky * 3;
    int yy = y + ky - 1, xx = x + kx - 1;
    float val = 0.f;
    if (yy >= 0 && yy < FH && xx >= 0 && xx < FW) val = fcyx[(size_t)ci * NPOS + yy * FW + xx];
    ((float*)&v)[j] = val;
  }
  *(float4*)&im[(size_t)idx * 4] = v;
}

// ---------------- merged RPN 1x1 convs: layer1[NPOS][512] x (Wloc||Wsc) ----------------
__global__ __launch_bounds__(256) void k_gemm_rpn(
    const float* __restrict__ A, const float* __restrict__ Wloc, const float* __restrict__ Wsc,
    const float* __restrict__ bloc, const float* __restrict__ bsc,
    float* __restrict__ rpnloc, float* __restrict__ rpnsc)
{
  __shared__ float As[16][68];
  __shared__ float Bs[16][68];
  int tid = threadIdx.x;
  int bm = blockIdx.x * 64;
  int tx = tid & 15, ty = tid >> 4;
  float acc[4][4] = {};
  int lr = tid >> 2, lk = (tid & 3) * 4;
  int ar = bm + lr; if (ar >= NPOS) ar = NPOS - 1;
  const float* ap = A + (size_t)ar * 512 + lk;
  const float* bp;
  if (lr < 36)      bp = Wloc + (size_t)lr * 512 + lk;
  else if (lr < 54) bp = Wsc + (size_t)(lr - 36) * 512 + lk;
  else              bp = Wsc + lk;   // dummy row, output discarded
  for (int k0 = 0; k0 < 512; k0 += 16) {
    float4 av = *(const float4*)(ap + k0);
    float4 bv = *(const float4*)(bp + k0);
    As[lk + 0][lr] = av.x; As[lk + 1][lr] = av.y; As[lk + 2][lr] = av.z; As[lk + 3][lr] = av.w;
    Bs[lk + 0][lr] = bv.x; Bs[lk + 1][lr] = bv.y; Bs[lk + 2][lr] = bv.z; Bs[lk + 3][lr] = bv.w;
    __syncthreads();
    #pragma unroll
    for (int k = 0; k < 16; ++k) {
      float4 a = *(const float4*)&As[k][ty * 4];
      float4 b = *(const float4*)&Bs[k][tx * 4];
      acc[0][0] += a.x * b.x; acc[0][1] += a.x * b.y; acc[0][2] += a.x * b.z; acc[0][3] += a.x * b.w;
      acc[1][0] += a.y * b.x; acc[1][1] += a.y * b.y; acc[1][2] += a.y * b.z; acc[1][3] += a.y * b.w;
      acc[2][0] += a.z * b.x; acc[2][1] += a.z * b.y; acc[2][2] += a.z * b.z; acc[2][3] += a.z * b.w;
      acc[3][0] += a.w * b.x; acc[3][1] += a.w * b.y; acc[3][2] += a.w * b.z; acc[3][3] += a.w * b.w;
    }
    __syncthreads();
  }
  #pragma unroll
  for (int i = 0; i < 4; ++i) {
    int m = bm + ty * 4 + i;
    if (m >= NPOS) continue;
    #pragma unroll
    for (int j = 0; j < 4; ++j) {
      int n = tx * 4 + j;
      if (n < 36)      rpnloc[(size_t)m * 36 + n] = acc[i][j] + bloc[n];
      else if (n < 54) rpnsc[(size_t)m * 18 + (n - 36)] = acc[i][j] + bsc[n - 36];
    }
  }
}

// ---------------- proposals: decode boxes, clip, validity, sort keys ----------------
__global__ __launch_bounds__(256) void k_proposal(
    const float* __restrict__ rpnloc, const float* __restrict__ rpnsc,
    const void* __restrict__ scalep, float4* __restrict__ roi_all,
    unsigned long long* __restrict__ keys)
{
  int a = blockIdx.x * 256 + threadIdx.x;
  if (a >= NANCH) return;
  int s = a / 9, t = a - s * 9;
  int iy = s / FW, ix = s - iy * FW;
  float sy = iy * 16.f, sx = ix * 16.f;
  float ay1 = c_AB[t][0] + sy, ax1 = c_AB[t][1] + sx;
  float ay2 = c_AB[t][2] + sy, ax2 = c_AB[t][3] + sx;
  const float* lp = rpnloc + (size_t)s * 36 + t * 4;
  float dy = lp[0], dx = lp[1], dh = lp[2], dw = lp[3];
  float ph = ay2 - ay1, pw = ax2 - ax1;
  float py = ay1 + 0.5f * ph, px = ax1 + 0.5f * pw;
  float cy = dy * ph + py, cx = dx * pw + px;
  float hh = expf(dh) * ph, ww = expf(dw) * pw;
  float y1 = cy - 0.5f * hh, x1 = cx - 0.5f * ww;
  float y2 = cy + 0.5f * hh, x2 = cx + 0.5f * ww;
  y1 = fminf(fmaxf(y1, 0.f), (float)HIMG); y2 = fminf(fmaxf(y2, 0.f), (float)HIMG);
  x1 = fminf(fmaxf(x1, 0.f), (float)WIMG); x2 = fminf(fmaxf(x2, 0.f), (float)WIMG);
  int iv = *(const int*)scalep;
  float scale = (iv >= 1 && iv < 1000000) ? (float)iv : *(const float*)scalep;
  float minsz = 16.f * scale;
  bool valid = (y2 - y1 >= minsz) && (x2 - x1 >= minsz);
  float fg = rpnsc[(size_t)s * 18 + t * 2 + 1];
  float sc = valid ? fg : __uint_as_float(0xFF800000u);   // -inf
  unsigned u = __float_as_uint(sc);
  u = (u & 0x80000000u) ? ~u : (u | 0x80000000u);         // order-preserving uint
  keys[a] = (((unsigned long long)(~u)) << 32) | (unsigned)a;  // asc sort == desc score, ties by idx
  roi_all[a] = make_float4(y1, x1, y2, x2);
}

// ---------------- single-block top-2000: radix select + LDS bitonic ----------------
__global__ __launch_bounds__(1024) void k_topk(
    const unsigned long long* __restrict__ keys, const float4* __restrict__ roi_all,
    float4* __restrict__ boxes, int* __restrict__ vbs)
{
  __shared__ unsigned int hist[256];
  __shared__ unsigned long long prefix;
  __shared__ int rankr;
  __shared__ int cnt;
  __shared__ unsigned long long sk[2048];
  int tid = threadIdx.x;
  if (tid == 0) { prefix = 0ULL; rankr = PRE - 1; }
  __syncthreads();
  for (int p = 7; p >= 0; --p) {
    if (tid < 256) hist[tid] = 0;
    __syncthreads();
    unsigned long long pref = prefix;
    int shift = (p + 1) * 8;
    for (int i = tid; i < NANCH; i += 1024) {
      unsigned long long k = keys[i];
      bool match = (p == 7) || ((k >> shift) == (pref >> shift));
      if (match) atomicAdd(&hist[(unsigned)(k >> (p * 8)) & 255u], 1u);
    }
    __syncthreads();
    if (tid == 0) {
      int r = rankr;
      unsigned cum = 0;
      for (int b2 = 0; b2 < 256; ++b2) {
        unsigned c = hist[b2];
        if (cum + c > (unsigned)r) { prefix |= ((unsigned long long)b2) << (p * 8); rankr = r - (int)cum; break; }
        cum += c;
      }
    }
    __syncthreads();
  }
  unsigned long long kth = prefix;
  if (tid == 0) cnt = 0;
  __syncthreads();
  for (int i = tid; i < NANCH; i += 1024) {
    unsigned long long k = keys[i];
    if (k <= kth) {
      int pos = atomicAdd(&cnt, 1);
      if (pos < 2048) sk[pos] = k;
    }
  }
  __syncthreads();
  if (tid < 48) sk[2000 + tid] = ~0ULL;
  __syncthreads();
  for (int size = 2; size <= 2048; size <<= 1) {
    for (int stride = size >> 1; stride > 0; stride >>= 1) {
      int i = 2 * tid - (tid & (stride - 1));
      int j = i + stride;
      unsigned long long a = sk[i], b = sk[j];
      bool asc = ((i & size) == 0);
      bool sw = asc ? (a > b) : (a < b);
      __syncthreads();
      if (sw) { sk[i] = b; sk[j] = a; }
      __syncthreads();
    }
  }
  for (int i = tid; i < PRE; i += 1024) {
    unsigned long long k = sk[i];
    int a = (int)(k & 0xFFFFFFFFULL);
    boxes[i] = roi_all[a];
    vbs[i] = ((unsigned)(k >> 32) < 0xFF800000u) ? 1 : 0;
  }
}

// ---------------- suppression bitmask ----------------
__global__ __launch_bounds__(64) void k_supmat(const float4* __restrict__ boxes,
                                               unsigned long long* __restrict__ supmat)
{
  int i = blockIdx.x;
  int lane = threadIdx.x;
  float4 bi = boxes[i];
  float ai = (bi.z - bi.x + 1.f) * (bi.w - bi.y + 1.f);
  for (int w = 0; w < 32; ++w) {
    int j = w * 64 + lane;
    bool sup = false;
    if (j < PRE && j > i) {
      float4 bj = boxes[j];
      float aj = (bj.z - bj.x + 1.f) * (bj.w - bj.y + 1.f);
      float iy1 = fmaxf(bi.x, bj.x), ix1 = fmaxf(bi.y, bj.y);
      float iy2 = fminf(bi.z, bj.z), ix2 = fminf(bi.w, bj.w);
      float ih = fmaxf(iy2 - iy1 + 1.f, 0.f), iw = fmaxf(ix2 - ix1 + 1.f, 0.f);
      float inter = ih * iw;
      float iou = inter / (ai + aj - inter);
      sup = iou > 0.7f;
    }
    unsigned long long word = __ballot(sup);
    if (lane == 0) supmat[(size_t)i * 32 + w] = word;
  }
}

// ---------------- sequential NMS scan + kept-first selection + rois write ----------------
__global__ __launch_bounds__(256) void k_nms(
    const unsigned long long* __restrict__ supmat, const int* __restrict__ vbs,
    const float4* __restrict__ boxes, float* __restrict__ rois_ws, float* __restrict__ out_rois)
{
  __shared__ unsigned long long rows[64][32];
  __shared__ unsigned long long removed[32];
  __shared__ unsigned long long keepw[32];
  __shared__ unsigned long long kmsh;
  __shared__ int pref[33];
  __shared__ int sel[2048];
  int tid = threadIdx.x;
  if (tid < 32) removed[tid] = 0ULL;
  __syncthreads();
  for (int b = 0; b < 32; ++b) {
    for (int t = tid; t < 2048; t += 256) {
      int k = t >> 5, w = t & 31;
      rows[k][w] = supmat[(size_t)(b * 64 + k) * 32 + w];
    }
    __syncthreads();
    if (tid < 64) {
      int lane = tid;
      int gj = b * 64 + lane;
      int vb = (gj < PRE) ? vbs[gj] : 0;
      unsigned long long vbw = __ballot(vb != 0);
      unsigned long long km = vbw & ~removed[b];
      unsigned long long Wj = rows[lane][b];
      for (int k = 0; k < 64; ++k) {
        unsigned long long wk = __shfl(Wj, k);
        if ((km >> k) & 1ULL) km &= ~wk;
      }
      if (lane == 0) { keepw[b] = km; kmsh = km; }
    }
    __syncthreads();
    {
      unsigned long long km = kmsh;
      int w = tid & 31, kb = (tid >> 5) * 8;
      unsigned long long acc = 0ULL;
      for (int k = kb; k < kb + 8; ++k)
        if ((km >> k) & 1ULL) acc |= rows[k][w];
      if (acc) atomicOr((unsigned long long*)&removed[w], acc);
    }
    __syncthreads();
  }
  if (tid == 0) {
    pref[0] = 0;
    for (int w = 0; w < 32; ++w) pref[w + 1] = pref[w] + __popcll(keepw[w]);
  }
  __syncthreads();
  if (tid < 32) {
    int w = tid;
    unsigned long long bits = keepw[w];
    int base = pref[w], r = 0;
    for (int bit = 0; bit < 64; ++bit)
      if ((bits >> bit) & 1ULL) { sel[base + r] = w * 64 + bit; r++; }
    int Kc = pref[32];
    unsigned long long mask = (w < 31) ? ~0ULL : 0xFFFFULL;     // 2000 = 31*64+16
    unsigned long long ub = ~keepw[w] & mask;
    int ubase = Kc + (w * 64 - pref[w]); r = 0;
    for (int bit = 0; bit < 64; ++bit)
      if ((ub >> bit) & 1ULL) { sel[ubase + r] = w * 64 + bit; r++; }
  }
  __syncthreads();
  for (int t = tid; t < POST; t += 256) {
    float4 bx = boxes[sel[t]];
    rois_ws[t * 4 + 0] = bx.x; rois_ws[t * 4 + 1] = bx.y;
    rois_ws[t * 4 + 2] = bx.z; rois_ws[t * 4 + 3] = bx.w;
    out_rois[t * 4 + 0] = bx.x; out_rois[t * 4 + 1] = bx.y;
    out_rois[t * 4 + 2] = bx.z; out_rois[t * 4 + 3] = bx.w;
  }
}

// ---------------- ROI adaptive max-pool 7x7 -> pool bf16 [300][512*49] ----------------
__global__ __launch_bounds__(256) void k_roipool(
    const float* __restrict__ feat_yxc, const float* __restrict__ rois,
    unsigned short* __restrict__ poolbf)
{
  int r = blockIdx.x, cg = blockIdx.y;
  int lane = threadIdx.x & 63, bslot = threadIdx.x >> 6;
  int c = cg * 64 + lane;
  float b0 = rois[r * 4 + 0], b1 = rois[r * 4 + 1], b2 = rois[r * 4 + 2], b3 = rois[r * 4 + 3];
  int y0 = min(max((int)floorf(b0 * 0.0625f), 0), FH - 1);
  int x0 = min(max((int)floorf(b1 * 0.0625f), 0), FW - 1);
  int y1 = min(max((int)floorf(b2 * 0.0625f), 0), FH - 1);
  int x1 = min(max((int)floorf(b3 * 0.0625f), 0), FW - 1);
  int Hh = y1 - y0 + 1, Ww = x1 - x0 + 1;
  for (int bin = bslot; bin < 49; bin += 4) {
    int by = bin / 7, bx = bin - by * 7;
    int rs = y0 + (by * Hh) / 7, re = y0 + ((by + 1) * Hh + 6) / 7;
    int cs = x0 + (bx * Ww) / 7, ce = x0 + ((bx + 1) * Ww + 6) / 7;
    float m = -1e30f;
    for (int y = rs; y < re; ++y)
      for (int x = cs; x < ce; ++x)
        m = fmaxf(m, feat_yxc[((size_t)(y * FW + x)) * 512 + c]);
    poolbf[(size_t)r * 25088 + c * 49 + bin] = f2bf(m);
  }
}

// ---------------- FC/heads bf16 MFMA GEMM, split-K, BM=160 x BN=128 ----------------
template<bool BBF16>
__global__ __launch_bounds__(512) void k_fcg(
    const unsigned short* __restrict__ A, const void* __restrict__ Bv,
    float* __restrict__ P, int K, int N)
{
  __shared__ unsigned short As[160 * 40];
  __shared__ unsigned short Bs[128 * 40];
  int tid = threadIdx.x;
  int bn = blockIdx.x * 128;
  int bm = blockIdx.y * 160;
  int sk2 = blockIdx.z;
  int KC = K >> 3;
  int k0beg = sk2 * KC, kend = k0beg + KC;
  int w = tid >> 6, lane = tid & 63;
  int wm = w >> 2, wn = w & 3;
  int l15 = lane & 15, lg = lane >> 4;
  int arow0 = tid >> 2, aq0 = tid & 3;
  int arow1 = 128 + (tid >> 2);
  int kr = tid >> 4, bm_ = tid & 15, nn = bm_ * 8;
  int bpos = (((kr >> 3) ^ (bm_ & 3)) << 3) | (kr & 7);
  const float* Bf = (const float*)Bv;
  const unsigned short* Bh = (const unsigned short*)Bv;

  f32x4 acc[5][2];
  #pragma unroll
  for (int a_ = 0; a_ < 5; ++a_) {
    acc[a_][0] = (f32x4){0.f, 0.f, 0.f, 0.f};
    acc[a_][1] = (f32x4){0.f, 0.f, 0.f, 0.f};
  }

  uint4 ra0, ra1, rbh;
  float4 rb0, rb1;
  ra0 = *(const uint4*)(A + (size_t)(bm + arow0) * K + k0beg + aq0 * 8);
  if (tid < 128) ra1 = *(const uint4*)(A + (size_t)(bm + arow1) * K + k0beg + aq0 * 8);
  if (BBF16) rbh = *(const uint4*)(Bh + (size_t)(k0beg + kr) * N + bn + nn);
  else {
    rb0 = *(const float4*)(Bf + (size_t)(k0beg + kr) * N + bn + nn);
    rb1 = *(const float4*)(Bf + (size_t)(k0beg + kr) * N + bn + nn + 4);
  }

  for (int k0 = k0beg; k0 < kend; k0 += 32) {
    *(uint4*)(&As[arow0 * 40 + aq0 * 8]) = ra0;
    if (tid < 128) *(uint4*)(&As[arow1 * 40 + aq0 * 8]) = ra1;
    {
      unsigned short bb[8];
      if (BBF16) {
        const unsigned short* pp = (const unsigned short*)&rbh;
        #pragma unroll
        for (int j = 0; j < 8; ++j) bb[j] = pp[j];
      } else {
        bb[0] = f2bf(rb0.x); bb[1] = f2bf(rb0.y); bb[2] = f2bf(rb0.z); bb[3] = f2bf(rb0.w);
        bb[4] = f2bf(rb1.x); bb[5] = f2bf(rb1.y); bb[6] = f2bf(rb1.z); bb[7] = f2bf(rb1.w);
      }
      #pragma unroll
      for (int j = 0; j < 8; ++j) Bs[(nn + j) * 40 + bpos] = bb[j];
    }
    __syncthreads();
    if (k0 + 32 < kend) {
      ra0 = *(const uint4*)(A + (size_t)(bm + arow0) * K + k0 + 32 + aq0 * 8);
      if (tid < 128) ra1 = *(const uint4*)(A + (size_t)(bm + arow1) * K + k0 + 32 + aq0 * 8);
      if (BBF16) rbh = *(const uint4*)(Bh + (size_t)(k0 + 32 + kr) * N + bn + nn);
      else {
        rb0 = *(const float4*)(Bf + (size_t)(k0 + 32 + kr) * N + bn + nn);
        rb1 = *(const float4*)(Bf + (size_t)(k0 + 32 + kr) * N + bn + nn + 4);
      }
    }
    bf16x8 bf[2];
    #pragma unroll
    for (int ns = 0; ns < 2; ++ns) {
      int n = wn * 32 + ns * 16 + l15;
      int g = lg ^ ((n >> 3) & 3);
      bf[ns] = *(const bf16x8*)(&Bs[n * 40 + g * 8]);
    }
    #pragma unroll
    for (int mt = 0; mt < 5; ++mt) {
      int row = wm * 80 + mt * 16 + l15;
      bf16x8 af = *(const bf16x8*)(&As[row * 40 + lg * 8]);
      acc[mt][0] = __builtin_amdgcn_mfma_f32_16x16x32_bf16(af, bf[0], acc[mt][0], 0, 0, 0);
      acc[mt][1] = __builtin_amdgcn_mfma_f32_16x16x32_bf16(af, bf[1], acc[mt][1], 0, 0, 0);
    }
    __syncthreads();
  }
  float* Pp = P + (size_t)sk2 * 320 * N;
  #pragma unroll
  for (int mt = 0; mt < 5; ++mt)
    #pragma unroll
    for (int ns = 0; ns < 2; ++ns)
      #pragma unroll
      for (int r2 = 0; r2 < 4; ++r2) {
        int m = bm + wm * 80 + mt * 16 + lg * 4 + r2;
        int n = bn + wn * 32 + ns * 16 + l15;
        Pp[(size_t)m * N + n] = acc[mt][ns][r2];
      }
}

// ---------------- pack Wl||Ws -> bf16 [4096][128] ----------------
__global__ __launch_bounds__(256) void k_wpack(
    const float* __restrict__ Wl, const float* __restrict__ Wsv, unsigned short* __restrict__ Wcat)
{
  int idx = blockIdx.x * 256 + threadIdx.x;
  if (idx >= 4096 * 128) return;
  int k = idx >> 7, n = idx & 127;
  float v = 0.f;
  if (n < 84) v = Wl[(size_t)k * 84 + n];
  else if (n < 105) v = Wsv[(size_t)k * 21 + (n - 84)];
  Wcat[idx] = f2bf(v);
}

// ---------------- heads reduce: sum 8 partials + bias -> out ----------------
__global__ __launch_bounds__(256) void k_headreduce(
    const float* __restrict__ P, const float* __restrict__ bl, const float* __restrict__ bs,
    float* __restrict__ out)
{
  int idx = blockIdx.x * 256 + threadIdx.x;
  if (idx >= 300 * 105) return;
  int m = idx / 105, n = idx - m * 105;
  float s = 0.f;
  #pragma unroll
  for (int s2 = 0; s2 < 8; ++s2) s += P[(size_t)s2 * 320 * 128 + m * 128 + n];
  if (n < 84) out[(size_t)m * 84 + n] = s + bl[n];
  else        out[25200 + (size_t)m * 21 + (n - 84)] = s + bs[n - 84];
}

// ---------------- reduce split-K partials ----------------
__global__ __launch_bounds__(256) void k_reduce1(
    const float* __restrict__ P, const float* __restrict__ b1, unsigned short* __restrict__ h1bf)
{
  int idx = blockIdx.x * 256 + threadIdx.x;
  if (idx >= 320 * 4096) return;
  int m = idx >> 12, n = idx & 4095;
  float s = b1[n];
  #pragma unroll
  for (int s2 = 0; s2 < 8; ++s2) s += P[(size_t)s2 * 320 * 4096 + idx];
  s = fmaxf(s, 0.f);
  h1bf[idx] = (m < 300) ? f2bf(s) : (unsigned short)0;
}

__global__ __launch_bounds__(256) void k_reduce2(
    const float* __restrict__ P, const float* __restrict__ b2, unsigned short* __restrict__ fc7bf)
{
  int idx = blockIdx.x * 256 + threadIdx.x;
  if (idx >= 300 * 4096) return;
  int n = idx & 4095;
  float s = b2[n];
  #pragma unroll
  for (int s2 = 0; s2 < 8; ++s2) s += P[(size_t)s2 * 320 * 4096 + idx];
  fc7bf[idx] = f2bf(fmaxf(s, 0.f));
}

// ===========================================================================
extern "C" void kernel_launch(void* const* d_in, const int* in_sizes, int n_in,
                              void* d_out, int out_size, void* d_ws, size_t ws_size,
                              hipStream_t stream)
{
  const float* x    = (const float*)d_in[0];
  const float* Wext = (const float*)d_in[1];
  const float* Wc1  = (const float*)d_in[2];
  const float* bc1  = (const float*)d_in[3];
  const float* Wloc = (const float*)d_in[4];
  const float* bloc = (const float*)d_in[5];
  const float* Wsc  = (const float*)d_in[6];
  const float* bsc  = (const float*)d_in[7];
  const float* W1   = (const float*)d_in[8];
  const float* b1   = (const float*)d_in[9];
  const float* W2   = (const float*)d_in[10];
  const float* b2   = (const float*)d_in[11];
  const float* Wl   = (const float*)d_in[12];
  const float* bl   = (const float*)d_in[13];
  const float* Wsv  = (const float*)d_in[14];
  const float* bs   = (const float*)d_in[15];
  const void*  scalep = d_in[16];
  float* out = (float*)d_out;
  char* ws = (char*)d_ws;

  // All regions dedicated (no aliasing; ws_size ~1.6 GB, usage ~156 MB).
  size_t off = 0;
  auto alloc = [&](size_t b) { size_t o = off; off += (b + 255) & ~(size_t)255; return o; };
  size_t o_featyxc = alloc((size_t)NPOS * 512 * 4);
  size_t o_featcyx = alloc((size_t)512 * NPOS * 4);
  size_t o_layer1  = alloc((size_t)NPOS * 512 * 4);
  size_t o_rpnloc  = alloc((size_t)NPOS * 36 * 4);
  size_t o_rpnsc   = alloc((size_t)NPOS * 18 * 4);
  size_t o_roiall  = alloc((size_t)NANCH * 16);
  size_t o_keys    = alloc((size_t)NANCH * 8);
  size_t o_boxes   = alloc((size_t)PRE * 16);
  size_t o_vbs     = alloc((size_t)PRE * 4);
  size_t o_supmat  = alloc((size_t)PRE * 32 * 8);
  size_t o_rois    = alloc((size_t)POST * 16);
  size_t o_poolbf  = alloc((size_t)320 * 25088 * 2);
  size_t o_h1bf    = alloc((size_t)320 * 4096 * 2);
  size_t o_wcat    = alloc((size_t)4096 * 128 * 2);
  size_t o_imx     = alloc((size_t)NPOS * 4608 * 4);
  size_t o_cpart   = alloc((size_t)4 * NPOS * 512 * 4);
  size_t o_part    = alloc((size_t)8 * 320 * 4096 * 4);
  (void)ws_size; (void)in_sizes; (void)n_in; (void)out_size;

  float* feat_yxc = (float*)(ws + o_featyxc);
  float* feat_cyx = (float*)(ws + o_featcyx);
  float* layer1   = (float*)(ws + o_layer1);
  float* rpnloc   = (float*)(ws + o_rpnloc);
  float* rpnsc    = (float*)(ws + o_rpnsc);
  float4* roi_all = (float4*)(ws + o_roiall);
  unsigned long long* keys = (unsigned long long*)(ws + o_keys);
  float4* boxes   = (float4*)(ws + o_boxes);
  int* vbs        = (int*)(ws + o_vbs);
  unsigned long long* supmat = (unsigned long long*)(ws + o_supmat);
  float* rois     = (float*)(ws + o_rois);
  unsigned short* poolbf = (unsigned short*)(ws + o_poolbf);
  unsigned short* h1bf   = (unsigned short*)(ws + o_h1bf);
  unsigned short* wcat   = (unsigned short*)(ws + o_wcat);
  float* imx      = (float*)(ws + o_imx);
  float* cpart    = (float*)(ws + o_cpart);
  float* partials = (float*)(ws + o_part);

  // pack head weights (independent)
  k_wpack<<<(4096 * 128) / 256, 256, 0, stream>>>(Wl, Wsv, wcat);
  // feature extractor (16x16 stride-16 patch conv) + relu  [split-K=4]
  k_imext<<<(NPOS * 768) / 256, 256, 0, stream>>>(x, imx);
  k_gemm_sk<<<dim3(19, 8, 4), 256, 0, stream>>>(imx, Wext, cpart, NPOS, 768, 192);
  k_reduce_conv<false><<<(NPOS * 128 + 255) / 256, 256, 0, stream>>>(cpart, nullptr, feat_yxc, NPOS);
  k_transpose<<<dim3(75, 16), 256, 0, stream>>>(feat_yxc, feat_cyx);
  // 3x3 conv 512->512 SAME + bias + relu (fp32 for score exactness) [split-K=4]
  k_imcol<<<(NPOS * 1152) / 256, 256, 0, stream>>>(feat_cyx, imx);
  k_gemm_sk<<<dim3(19, 8, 4), 256, 0, stream>>>(imx, Wc1, cpart, NPOS, 4608, 1152);
  k_reduce_conv<true><<<(NPOS * 128 + 255) / 256, 256, 0, stream>>>(cpart, bc1, layer1, NPOS);
  // merged RPN 1x1 convs (fp32, identical accumulation order to the split pair)
  k_gemm_rpn<<<38, 256, 0, stream>>>(layer1, Wloc, Wsc, bloc, bsc, rpnloc, rpnsc);
  // proposals -> top-2000 -> NMS -> rois
  k_proposal<<<(NANCH + 255) / 256, 256, 0, stream>>>(rpnloc, rpnsc, scalep, roi_all, keys);
  k_topk<<<1, 1024, 0, stream>>>(keys, roi_all, boxes, vbs);
  k_supmat<<<PRE, 64, 0, stream>>>(boxes, supmat);
  k_nms<<<1, 256, 0, stream>>>(supmat, vbs, boxes, rois, out + 31500);
  // ROI max-pool -> bf16 pool rows 0..299 (rows 300..319 discarded by reduce1)
  k_roipool<<<dim3(POST, 8), 256, 0, stream>>>(feat_yxc, rois, poolbf);
  // FC1 -> relu -> FC2 -> relu -> heads (bf16 MFMA, split-K=8)
  k_fcg<false><<<dim3(32, 2, 8), 512, 0, stream>>>(poolbf, W1, partials, 25088, 4096);
  k_reduce1<<<(320 * 4096) / 256, 256, 0, stream>>>(partials, b1, h1bf);
  k_fcg<false><<<dim3(32, 2, 8), 512, 0, stream>>>(h1bf, W2, partials, 4096, 4096);
  k_reduce2<<<(300 * 4096) / 256, 256, 0, stream>>>(partials, b2, h1bf);
  k_fcg<true><<<dim3(1, 2, 8), 512, 0, stream>>>(h1bf, wcat, partials, 4096, 128);
  k_headreduce<<<(300 * 105 + 255) / 256, 256, 0, stream>>>(partials, bl, bs, out);
}

// Round 10
// 769.909 us; speedup vs baseline: 9.8045x; 1.0975x over previous
//
#include <hip/hip_runtime.h>
#include <stdint.h>

#define FH 38
#define FW 63
#define NPOS 2394           // 38*63
#define NANCH 21546         // NPOS*9
#define HIMG 608
#define WIMG 1008
#define PRE 2000
#define POST 300

typedef __attribute__((ext_vector_type(8))) short bf16x8;
typedef __attribute__((ext_vector_type(4))) float f32x4;

__device__ __constant__ float c_AB[9][4] = {
  {-37.254833f,-82.50967f,53.254833f,98.50967f},
  {-82.50967f,-173.01933f,98.50967f,189.01933f},
  {-173.01933f,-354.03867f,189.01933f,370.03867f},
  {-56.f,-56.f,72.f,72.f},
  {-120.f,-120.f,136.f,136.f},
  {-248.f,-248.f,264.f,264.f},
  {-82.50967f,-37.254833f,98.50967f,53.254833f},
  {-173.01933f,-82.50967f,189.01933f,98.50967f},
  {-354.03867f,-173.01933f,370.03867f,189.01933f}};

__device__ __forceinline__ unsigned short f2bf(float f) {
  unsigned u = __float_as_uint(f);
  u += 0x7FFFu + ((u >> 16) & 1u);
  return (unsigned short)(u >> 16);
}

// ---------------- pack Wc1 [512][512*9] (o,ci,r) -> [512][9*512] (o,r,ci) ----------------
// Proven correct in R6 (R6 passed; it was a perf failure, not a math failure).
__global__ __launch_bounds__(256) void k_wc1pack(const float* __restrict__ Wc1, float* __restrict__ Bp) {
  __shared__ float t[4608];
  int o = blockIdx.x;
  const float* src = Wc1 + (size_t)o * 4608;
  for (int i = threadIdx.x; i < 4608; i += 256) t[i] = src[i];
  __syncthreads();
  float* dst = Bp + (size_t)o * 4608;
  for (int i = threadIdx.x; i < 4608; i += 256) {
    int r = i >> 9, ci = i & 511;
    dst[i] = t[ci * 9 + r];          // LDS stride-9 read: 2-way max, free
  }
}

// ---------------- fused-A split-K fp32 conv GEMM (8x4/thread, proven skeleton) --------
// MODE 0: ext. A[p][k], k=ci*256+ky*16+kx, read from x. B=Wext[512][768]. K=768.
// MODE 1: c1.  A[p][k'], k'=r*512+ci, read from feat_yxc (SAME pad). B=wc1p. K=4608.
// Skeleton = R5/R7/R9's k_gemm_sk verbatim (BM=128,BN=64,256thr,8x4,~84 VGPR);
// only the A-load addresses changed (per-STEP uniform r/ci decode, ~20 VALU per
// 512-FMA step). R6 proved the addressing math; R6/R8 proved 8x8 acc is fatal.
template<int MODE>
__global__ __launch_bounds__(256) void k_gemm_conv(
    const float* __restrict__ src, const float* __restrict__ B,
    float* __restrict__ P, int Kc)
{
  const int K = MODE ? 4608 : 768;
  __shared__ float As[16][132];
  __shared__ float Bs[16][68];
  int tid = threadIdx.x;
  int bm = blockIdx.x * 128, bn = blockIdx.y * 64;
  int k0 = blockIdx.z * Kc;
  int kend = k0 + Kc;
  int tx = tid & 15, ty = tid >> 4;
  float4 acc[8];
  #pragma unroll
  for (int i = 0; i < 8; ++i) acc[i] = make_float4(0.f, 0.f, 0.f, 0.f);
  int lr = tid >> 2, lk = (tid & 3) * 4;
  int ar0 = bm + lr;      if (ar0 >= NPOS) ar0 = NPOS - 1;
  int ar1 = bm + lr + 64; if (ar1 >= NPOS) ar1 = NPOS - 1;
  int py0 = ar0 / FW, px0 = ar0 - py0 * FW;
  int py1 = ar1 / FW, px1 = ar1 - py1 * FW;
  const float* bp = B + (size_t)(bn + lr) * K + lk;

  float4 ra0, ra1, rb;
  auto loadA = [&](int kk, float4& v0, float4& v1) {
    if (MODE == 0) {
      // kk is 16-aligned: ci, ky constant across the step; kx = lk..lk+3
      int ci = kk >> 8, ky = (kk >> 4) & 15;
      const float* base = src + (size_t)(ci * HIMG + ky) * WIMG + lk;
      v0 = *(const float4*)(base + (size_t)(py0 * 16) * WIMG + px0 * 16);
      v1 = *(const float4*)(base + (size_t)(py1 * 16) * WIMG + px1 * 16);
    } else {
      // kk 16-aligned, 512|r-boundaries => r constant across the step
      int r = kk >> 9, cb = (kk & 511) + lk;
      int q = r / 3;
      int dy = q - 1, dx = r - q * 3 - 1;
      int yy0 = py0 + dy, xx0 = px0 + dx;
      int yy1 = py1 + dy, xx1 = px1 + dx;
      v0 = ((unsigned)yy0 < FH && (unsigned)xx0 < FW)
           ? *(const float4*)(src + (((size_t)(yy0 * FW + xx0)) << 9) + cb)
           : make_float4(0.f, 0.f, 0.f, 0.f);
      v1 = ((unsigned)yy1 < FH && (unsigned)xx1 < FW)
           ? *(const float4*)(src + (((size_t)(yy1 * FW + xx1)) << 9) + cb)
           : make_float4(0.f, 0.f, 0.f, 0.f);
    }
  };
  loadA(k0, ra0, ra1);
  rb = *(const float4*)(bp + k0);

  for (; k0 < kend; k0 += 16) {
    As[lk + 0][lr] = ra0.x; As[lk + 1][lr] = ra0.y; As[lk + 2][lr] = ra0.z; As[lk + 3][lr] = ra0.w;
    As[lk + 0][lr + 64] = ra1.x; As[lk + 1][lr + 64] = ra1.y; As[lk + 2][lr + 64] = ra1.z; As[lk + 3][lr + 64] = ra1.w;
    Bs[lk + 0][lr] = rb.x; Bs[lk + 1][lr] = rb.y; Bs[lk + 2][lr] = rb.z; Bs[lk + 3][lr] = rb.w;
    __syncthreads();
    if (k0 + 16 < kend) {
      loadA(k0 + 16, ra0, ra1);
      rb = *(const float4*)(bp + k0 + 16);
    }
    #pragma unroll
    for (int k = 0; k < 16; ++k) {
      float4 aL = *(const float4*)&As[k][ty * 8];
      float4 aH = *(const float4*)&As[k][ty * 8 + 4];
      float4 b  = *(const float4*)&Bs[k][tx * 4];
      float av0 = aL.x, av1 = aL.y, av2 = aL.z, av3 = aL.w;
      float av4 = aH.x, av5 = aH.y, av6 = aH.z, av7 = aH.w;
      acc[0].x += av0 * b.x; acc[0].y += av0 * b.y; acc[0].z += av0 * b.z; acc[0].w += av0 * b.w;
      acc[1].x += av1 * b.x; acc[1].y += av1 * b.y; acc[1].z += av1 * b.z; acc[1].w += av1 * b.w;
      acc[2].x += av2 * b.x; acc[2].y += av2 * b.y; acc[2].z += av2 * b.z; acc[2].w += av2 * b.w;
      acc[3].x += av3 * b.x; acc[3].y += av3 * b.y; acc[3].z += av3 * b.z; acc[3].w += av3 * b.w;
      acc[4].x += av4 * b.x; acc[4].y += av4 * b.y; acc[4].z += av4 * b.z; acc[4].w += av4 * b.w;
      acc[5].x += av5 * b.x; acc[5].y += av5 * b.y; acc[5].z += av5 * b.z; acc[5].w += av5 * b.w;
      acc[6].x += av6 * b.x; acc[6].y += av6 * b.y; acc[6].z += av6 * b.z; acc[6].w += av6 * b.w;
      acc[7].x += av7 * b.x; acc[7].y += av7 * b.y; acc[7].z += av7 * b.z; acc[7].w += av7 * b.w;
    }
    __syncthreads();
  }
  float* Pp = P + (size_t)blockIdx.z * NPOS * 512;
  #pragma unroll
  for (int i = 0; i < 8; ++i) {
    int m = bm + ty * 8 + i;
    if (m < NPOS) *(float4*)&Pp[(size_t)m * 512 + bn + tx * 4] = acc[i];
  }
}

// ---------------- reduce split-K conv partials (+bias, relu) ----------------
template<bool BIAS, int S>
__global__ __launch_bounds__(256) void k_reduce_conv(
    const float* __restrict__ P, const float* __restrict__ bias,
    float* __restrict__ C)
{
  int i = blockIdx.x * 256 + threadIdx.x;      // float4 index
  if (i >= NPOS * 128) return;
  size_t stride = (size_t)NPOS * 512;
  float4 s = make_float4(0.f, 0.f, 0.f, 0.f);
  if (BIAS) s = *(const float4*)&bias[(i * 4) & 511];
  #pragma unroll
  for (int s2 = 0; s2 < S; ++s2) {
    float4 v = *(const float4*)&P[s2 * stride + (size_t)i * 4];
    s.x += v.x; s.y += v.y; s.z += v.z; s.w += v.w;
  }
  s.x = fmaxf(s.x, 0.f); s.y = fmaxf(s.y, 0.f); s.z = fmaxf(s.z, 0.f); s.w = fmaxf(s.w, 0.f);
  *(float4*)&C[(size_t)i * 4] = s;
}

// ---------------- merged RPN 1x1 convs: layer1[NPOS][512] x (Wloc||Wsc) ----------------
__global__ __launch_bounds__(256) void k_gemm_rpn(
    const float* __restrict__ A, const float* __restrict__ Wloc, const float* __restrict__ Wsc,
    const float* __restrict__ bloc, const float* __restrict__ bsc,
    float* __restrict__ rpnloc, float* __restrict__ rpnsc)
{
  __shared__ float As[16][68];
  __shared__ float Bs[16][68];
  int tid = threadIdx.x;
  int bm = blockIdx.x * 64;
  int tx = tid & 15, ty = tid >> 4;
  float acc[4][4] = {};
  int lr = tid >> 2, lk = (tid & 3) * 4;
  int ar = bm + lr; if (ar >= NPOS) ar = NPOS - 1;
  const float* ap = A + (size_t)ar * 512 + lk;
  const float* bp;
  if (lr < 36)      bp = Wloc + (size_t)lr * 512 + lk;
  else if (lr < 54) bp = Wsc + (size_t)(lr - 36) * 512 + lk;
  else              bp = Wsc + lk;   // dummy row, output discarded
  for (int k0 = 0; k0 < 512; k0 += 16) {
    float4 av = *(const float4*)(ap + k0);
    float4 bv = *(const float4*)(bp + k0);
    As[lk + 0][lr] = av.x; As[lk + 1][lr] = av.y; As[lk + 2][lr] = av.z; As[lk + 3][lr] = av.w;
    Bs[lk + 0][lr] = bv.x; Bs[lk + 1][lr] = bv.y; Bs[lk + 2][lr] = bv.z; Bs[lk + 3][lr] = bv.w;
    __syncthreads();
    #pragma unroll
    for (int k = 0; k < 16; ++k) {
      float4 a = *(const float4*)&As[k][ty * 4];
      float4 b = *(const float4*)&Bs[k][tx * 4];
      acc[0][0] += a.x * b.x; acc[0][1] += a.x * b.y; acc[0][2] += a.x * b.z; acc[0][3] += a.x * b.w;
      acc[1][0] += a.y * b.x; acc[1][1] += a.y * b.y; acc[1][2] += a.y * b.z; acc[1][3] += a.y * b.w;
      acc[2][0] += a.z * b.x; acc[2][1] += a.z * b.y; acc[2][2] += a.z * b.z; acc[2][3] += a.z * b.w;
      acc[3][0] += a.w * b.x; acc[3][1] += a.w * b.y; acc[3][2] += a.w * b.z; acc[3][3] += a.w * b.w;
    }
    __syncthreads();
  }
  #pragma unroll
  for (int i = 0; i < 4; ++i) {
    int m = bm + ty * 4 + i;
    if (m >= NPOS) continue;
    #pragma unroll
    for (int j = 0; j < 4; ++j) {
      int n = tx * 4 + j;
      if (n < 36)      rpnloc[(size_t)m * 36 + n] = acc[i][j] + bloc[n];
      else if (n < 54) rpnsc[(size_t)m * 18 + (n - 36)] = acc[i][j] + bsc[n - 36];
    }
  }
}

// ---------------- proposals: decode boxes, clip, validity, sort keys ----------------
__global__ __launch_bounds__(256) void k_proposal(
    const float* __restrict__ rpnloc, const float* __restrict__ rpnsc,
    const void* __restrict__ scalep, float4* __restrict__ roi_all,
    unsigned long long* __restrict__ keys)
{
  int a = blockIdx.x * 256 + threadIdx.x;
  if (a >= NANCH) return;
  int s = a / 9, t = a - s * 9;
  int iy = s / FW, ix = s - iy * FW;
  float sy = iy * 16.f, sx = ix * 16.f;
  float ay1 = c_AB[t][0] + sy, ax1 = c_AB[t][1] + sx;
  float ay2 = c_AB[t][2] + sy, ax2 = c_AB[t][3] + sx;
  const float* lp = rpnloc + (size_t)s * 36 + t * 4;
  float dy = lp[0], dx = lp[1], dh = lp[2], dw = lp[3];
  float ph = ay2 - ay1, pw = ax2 - ax1;
  float py = ay1 + 0.5f * ph, px = ax1 + 0.5f * pw;
  float cy = dy * ph + py, cx = dx * pw + px;
  float hh = expf(dh) * ph, ww = expf(dw) * pw;
  float y1 = cy - 0.5f * hh, x1 = cx - 0.5f * ww;
  float y2 = cy + 0.5f * hh, x2 = cx + 0.5f * ww;
  y1 = fminf(fmaxf(y1, 0.f), (float)HIMG); y2 = fminf(fmaxf(y2, 0.f), (float)HIMG);
  x1 = fminf(fmaxf(x1, 0.f), (float)WIMG); x2 = fminf(fmaxf(x2, 0.f), (float)WIMG);
  int iv = *(const int*)scalep;
  float scale = (iv >= 1 && iv < 1000000) ? (float)iv : *(const float*)scalep;
  float minsz = 16.f * scale;
  bool valid = (y2 - y1 >= minsz) && (x2 - x1 >= minsz);
  float fg = rpnsc[(size_t)s * 18 + t * 2 + 1];
  float sc = valid ? fg : __uint_as_float(0xFF800000u);   // -inf
  unsigned u = __float_as_uint(sc);
  u = (u & 0x80000000u) ? ~u : (u | 0x80000000u);         // order-preserving uint
  keys[a] = (((unsigned long long)(~u)) << 32) | (unsigned)a;  // asc sort == desc score, ties by idx
  roi_all[a] = make_float4(y1, x1, y2, x2);
}

// ---------------- single-block top-2000: radix select + LDS bitonic ----------------
__global__ __launch_bounds__(1024) void k_topk(
    const unsigned long long* __restrict__ keys, const float4* __restrict__ roi_all,
    float4* __restrict__ boxes, int* __restrict__ vbs)
{
  __shared__ unsigned int hist[256];
  __shared__ unsigned long long prefix;
  __shared__ int rankr;
  __shared__ int cnt;
  __shared__ unsigned long long sk[2048];
  int tid = threadIdx.x;
  if (tid == 0) { prefix = 0ULL; rankr = PRE - 1; }
  __syncthreads();
  for (int p = 7; p >= 0; --p) {
    if (tid < 256) hist[tid] = 0;
    __syncthreads();
    unsigned long long pref = prefix;
    int shift = (p + 1) * 8;
    for (int i = tid; i < NANCH; i += 1024) {
      unsigned long long k = keys[i];
      bool match = (p == 7) || ((k >> shift) == (pref >> shift));
      if (match) atomicAdd(&hist[(unsigned)(k >> (p * 8)) & 255u], 1u);
    }
    __syncthreads();
    if (tid == 0) {
      int r = rankr;
      unsigned cum = 0;
      for (int b2 = 0; b2 < 256; ++b2) {
        unsigned c = hist[b2];
        if (cum + c > (unsigned)r) { prefix |= ((unsigned long long)b2) << (p * 8); rankr = r - (int)cum; break; }
        cum += c;
      }
    }
    __syncthreads();
  }
  unsigned long long kth = prefix;
  if (tid == 0) cnt = 0;
  __syncthreads();
  for (int i = tid; i < NANCH; i += 1024) {
    unsigned long long k = keys[i];
    if (k <= kth) {
      int pos = atomicAdd(&cnt, 1);
      if (pos < 2048) sk[pos] = k;
    }
  }
  __syncthreads();
  if (tid < 48) sk[2000 + tid] = ~0ULL;
  __syncthreads();
  for (int size = 2; size <= 2048; size <<= 1) {
    for (int stride = size >> 1; stride > 0; stride >>= 1) {
      int i = 2 * tid - (tid & (stride - 1));
      int j = i + stride;
      unsigned long long a = sk[i], b = sk[j];
      bool asc = ((i & size) == 0);
      bool sw = asc ? (a > b) : (a < b);
      __syncthreads();
      if (sw) { sk[i] = b; sk[j] = a; }
      __syncthreads();
    }
  }
  for (int i = tid; i < PRE; i += 1024) {
    unsigned long long k = sk[i];
    int a = (int)(k & 0xFFFFFFFFULL);
    boxes[i] = roi_all[a];
    vbs[i] = ((unsigned)(k >> 32) < 0xFF800000u) ? 1 : 0;
  }
}

// ---------------- suppression bitmask ----------------
__global__ __launch_bounds__(64) void k_supmat(const float4* __restrict__ boxes,
                                               unsigned long long* __restrict__ supmat)
{
  int i = blockIdx.x;
  int lane = threadIdx.x;
  float4 bi = boxes[i];
  float ai = (bi.z - bi.x + 1.f) * (bi.w - bi.y + 1.f);
  for (int w = 0; w < 32; ++w) {
    int j = w * 64 + lane;
    bool sup = false;
    if (j < PRE && j > i) {
      float4 bj = boxes[j];
      float aj = (bj.z - bj.x + 1.f) * (bj.w - bj.y + 1.f);
      float iy1 = fmaxf(bi.x, bj.x), ix1 = fmaxf(bi.y, bj.y);
      float iy2 = fminf(bi.z, bj.z), ix2 = fminf(bi.w, bj.w);
      float ih = fmaxf(iy2 - iy1 + 1.f, 0.f), iw = fmaxf(ix2 - ix1 + 1.f, 0.f);
      float inter = ih * iw;
      float iou = inter / (ai + aj - inter);
      sup = iou > 0.7f;
    }
    unsigned long long word = __ballot(sup);
    if (lane == 0) supmat[(size_t)i * 32 + w] = word;
  }
}

// ---------------- sequential NMS scan + kept-first selection + rois write ----------------
__global__ __launch_bounds__(256) void k_nms(
    const unsigned long long* __restrict__ supmat, const int* __restrict__ vbs,
    const float4* __restrict__ boxes, float* __restrict__ rois_ws, float* __restrict__ out_rois)
{
  __shared__ unsigned long long rows[64][32];
  __shared__ unsigned long long removed[32];
  __shared__ unsigned long long keepw[32];
  __shared__ unsigned long long kmsh;
  __shared__ int pref[33];
  __shared__ int sel[2048];
  int tid = threadIdx.x;
  if (tid < 32) removed[tid] = 0ULL;
  __syncthreads();
  for (int b = 0; b < 32; ++b) {
    for (int t = tid; t < 2048; t += 256) {
      int k = t >> 5, w = t & 31;
      rows[k][w] = supmat[(size_t)(b * 64 + k) * 32 + w];
    }
    __syncthreads();
    if (tid < 64) {
      int lane = tid;
      int gj = b * 64 + lane;
      int vb = (gj < PRE) ? vbs[gj] : 0;
      unsigned long long vbw = __ballot(vb != 0);
      unsigned long long km = vbw & ~removed[b];
      unsigned long long Wj = rows[lane][b];
      for (int k = 0; k < 64; ++k) {
        unsigned long long wk = __shfl(Wj, k);
        if ((km >> k) & 1ULL) km &= ~wk;
      }
      if (lane == 0) { keepw[b] = km; kmsh = km; }
    }
    __syncthreads();
    {
      unsigned long long km = kmsh;
      int w = tid & 31, kb = (tid >> 5) * 8;
      unsigned long long acc = 0ULL;
      for (int k = kb; k < kb + 8; ++k)
        if ((km >> k) & 1ULL) acc |= rows[k][w];
      if (acc) atomicOr((unsigned long long*)&removed[w], acc);
    }
    __syncthreads();
  }
  if (tid == 0) {
    pref[0] = 0;
    for (int w = 0; w < 32; ++w) pref[w + 1] = pref[w] + __popcll(keepw[w]);
  }
  __syncthreads();
  if (tid < 32) {
    int w = tid;
    unsigned long long bits = keepw[w];
    int base = pref[w], r = 0;
    for (int bit = 0; bit < 64; ++bit)
      if ((bits >> bit) & 1ULL) { sel[base + r] = w * 64 + bit; r++; }
    int Kc = pref[32];
    unsigned long long mask = (w < 31) ? ~0ULL : 0xFFFFULL;     // 2000 = 31*64+16
    unsigned long long ub = ~keepw[w] & mask;
    int ubase = Kc + (w * 64 - pref[w]); r = 0;
    for (int bit = 0; bit < 64; ++bit)
      if ((ub >> bit) & 1ULL) { sel[ubase + r] = w * 64 + bit; r++; }
  }
  __syncthreads();
  for (int t = tid; t < POST; t += 256) {
    float4 bx = boxes[sel[t]];
    rois_ws[t * 4 + 0] = bx.x; rois_ws[t * 4 + 1] = bx.y;
    rois_ws[t * 4 + 2] = bx.z; rois_ws[t * 4 + 3] = bx.w;
    out_rois[t * 4 + 0] = bx.x; out_rois[t * 4 + 1] = bx.y;
    out_rois[t * 4 + 2] = bx.z; out_rois[t * 4 + 3] = bx.w;
  }
}

// ---------------- ROI adaptive max-pool 7x7 -> pool bf16 [300][512*49] ----------------
__global__ __launch_bounds__(256) void k_roipool(
    const float* __restrict__ feat_yxc, const float* __restrict__ rois,
    unsigned short* __restrict__ poolbf)
{
  int r = blockIdx.x, cg = blockIdx.y;
  int lane = threadIdx.x & 63, bslot = threadIdx.x >> 6;
  int c = cg * 64 + lane;
  float b0 = rois[r * 4 + 0], b1 = rois[r * 4 + 1], b2 = rois[r * 4 + 2], b3 = rois[r * 4 + 3];
  int y0 = min(max((int)floorf(b0 * 0.0625f), 0), FH - 1);
  int x0 = min(max((int)floorf(b1 * 0.0625f), 0), FW - 1);
  int y1 = min(max((int)floorf(b2 * 0.0625f), 0), FH - 1);
  int x1 = min(max((int)floorf(b3 * 0.0625f), 0), FW - 1);
  int Hh = y1 - y0 + 1, Ww = x1 - x0 + 1;
  for (int bin = bslot; bin < 49; bin += 4) {
    int by = bin / 7, bx = bin - by * 7;
    int rs = y0 + (by * Hh) / 7, re = y0 + ((by + 1) * Hh + 6) / 7;
    int cs = x0 + (bx * Ww) / 7, ce = x0 + ((bx + 1) * Ww + 6) / 7;
    float m = -1e30f;
    for (int y = rs; y < re; ++y)
      for (int x = cs; x < ce; ++x)
        m = fmaxf(m, feat_yxc[((size_t)(y * FW + x)) * 512 + c]);
    poolbf[(size_t)r * 25088 + c * 49 + bin] = f2bf(m);
  }
}

// ---------------- FC/heads bf16 MFMA GEMM, split-K, BM=160 x BN=128 ----------------
template<bool BBF16>
__global__ __launch_bounds__(512) void k_fcg(
    const unsigned short* __restrict__ A, const void* __restrict__ Bv,
    float* __restrict__ P, int K, int N)
{
  __shared__ unsigned short As[160 * 40];
  __shared__ unsigned short Bs[128 * 40];
  int tid = threadIdx.x;
  int bn = blockIdx.x * 128;
  int bm = blockIdx.y * 160;
  int sk2 = blockIdx.z;
  int KC = K >> 3;
  int k0beg = sk2 * KC, kend = k0beg + KC;
  int w = tid >> 6, lane = tid & 63;
  int wm = w >> 2, wn = w & 3;
  int l15 = lane & 15, lg = lane >> 4;
  int arow0 = tid >> 2, aq0 = tid & 3;
  int arow1 = 128 + (tid >> 2);
  int kr = tid >> 4, bm_ = tid & 15, nn = bm_ * 8;
  int bpos = (((kr >> 3) ^ (bm_ & 3)) << 3) | (kr & 7);
  const float* Bf = (const float*)Bv;
  const unsigned short* Bh = (const unsigned short*)Bv;

  f32x4 acc[5][2];
  #pragma unroll
  for (int a_ = 0; a_ < 5; ++a_) {
    acc[a_][0] = (f32x4){0.f, 0.f, 0.f, 0.f};
    acc[a_][1] = (f32x4){0.f, 0.f, 0.f, 0.f};
  }

  uint4 ra0, ra1, rbh;
  float4 rb0, rb1;
  ra0 = *(const uint4*)(A + (size_t)(bm + arow0) * K + k0beg + aq0 * 8);
  if (tid < 128) ra1 = *(const uint4*)(A + (size_t)(bm + arow1) * K + k0beg + aq0 * 8);
  if (BBF16) rbh = *(const uint4*)(Bh + (size_t)(k0beg + kr) * N + bn + nn);
  else {
    rb0 = *(const float4*)(Bf + (size_t)(k0beg + kr) * N + bn + nn);
    rb1 = *(const float4*)(Bf + (size_t)(k0beg + kr) * N + bn + nn + 4);
  }

  for (int k0 = k0beg; k0 < kend; k0 += 32) {
    *(uint4*)(&As[arow0 * 40 + aq0 * 8]) = ra0;
    if (tid < 128) *(uint4*)(&As[arow1 * 40 + aq0 * 8]) = ra1;
    {
      unsigned short bb[8];
      if (BBF16) {
        const unsigned short* pp = (const unsigned short*)&rbh;
        #pragma unroll
        for (int j = 0; j < 8; ++j) bb[j] = pp[j];
      } else {
        bb[0] = f2bf(rb0.x); bb[1] = f2bf(rb0.y); bb[2] = f2bf(rb0.z); bb[3] = f2bf(rb0.w);
        bb[4] = f2bf(rb1.x); bb[5] = f2bf(rb1.y); bb[6] = f2bf(rb1.z); bb[7] = f2bf(rb1.w);
      }
      #pragma unroll
      for (int j = 0; j < 8; ++j) Bs[(nn + j) * 40 + bpos] = bb[j];
    }
    __syncthreads();
    if (k0 + 32 < kend) {
      ra0 = *(const uint4*)(A + (size_t)(bm + arow0) * K + k0 + 32 + aq0 * 8);
      if (tid < 128) ra1 = *(const uint4*)(A + (size_t)(bm + arow1) * K + k0 + 32 + aq0 * 8);
      if (BBF16) rbh = *(const uint4*)(Bh + (size_t)(k0 + 32 + kr) * N + bn + nn);
      else {
        rb0 = *(const float4*)(Bf + (size_t)(k0 + 32 + kr) * N + bn + nn);
        rb1 = *(const float4*)(Bf + (size_t)(k0 + 32 + kr) * N + bn + nn + 4);
      }
    }
    bf16x8 bf[2];
    #pragma unroll
    for (int ns = 0; ns < 2; ++ns) {
      int n = wn * 32 + ns * 16 + l15;
      int g = lg ^ ((n >> 3) & 3);
      bf[ns] = *(const bf16x8*)(&Bs[n * 40 + g * 8]);
    }
    #pragma unroll
    for (int mt = 0; mt < 5; ++mt) {
      int row = wm * 80 + mt * 16 + l15;
      bf16x8 af = *(const bf16x8*)(&As[row * 40 + lg * 8]);
      acc[mt][0] = __builtin_amdgcn_mfma_f32_16x16x32_bf16(af, bf[0], acc[mt][0], 0, 0, 0);
      acc[mt][1] = __builtin_amdgcn_mfma_f32_16x16x32_bf16(af, bf[1], acc[mt][1], 0, 0, 0);
    }
    __syncthreads();
  }
  float* Pp = P + (size_t)sk2 * 320 * N;
  #pragma unroll
  for (int mt = 0; mt < 5; ++mt)
    #pragma unroll
    for (int ns = 0; ns < 2; ++ns)
      #pragma unroll
      for (int r2 = 0; r2 < 4; ++r2) {
        int m = bm + wm * 80 + mt * 16 + lg * 4 + r2;
        int n = bn + wn * 32 + ns * 16 + l15;
        Pp[(size_t)m * N + n] = acc[mt][ns][r2];
      }
}

// ---------------- pack Wl||Ws -> bf16 [4096][128] ----------------
__global__ __launch_bounds__(256) void k_wpack(
    const float* __restrict__ Wl, const float* __restrict__ Wsv, unsigned short* __restrict__ Wcat)
{
  int idx = blockIdx.x * 256 + threadIdx.x;
  if (idx >= 4096 * 128) return;
  int k = idx >> 7, n = idx & 127;
  float v = 0.f;
  if (n < 84) v = Wl[(size_t)k * 84 + n];
  else if (n < 105) v = Wsv[(size_t)k * 21 + (n - 84)];
  Wcat[idx] = f2bf(v);
}

// ---------------- heads reduce: sum 8 partials + bias -> out ----------------
__global__ __launch_bounds__(256) void k_headreduce(
    const float* __restrict__ P, const float* __restrict__ bl, const float* __restrict__ bs,
    float* __restrict__ out)
{
  int idx = blockIdx.x * 256 + threadIdx.x;
  if (idx >= 300 * 105) return;
  int m = idx / 105, n = idx - m * 105;
  float s = 0.f;
  #pragma unroll
  for (int s2 = 0; s2 < 8; ++s2) s += P[(size_t)s2 * 320 * 128 + m * 128 + n];
  if (n < 84) out[(size_t)m * 84 + n] = s + bl[n];
  else        out[25200 + (size_t)m * 21 + (n - 84)] = s + bs[n - 84];
}

// ---------------- reduce split-K partials ----------------
__global__ __launch_bounds__(256) void k_reduce1(
    const float* __restrict__ P, const float* __restrict__ b1, unsigned short* __restrict__ h1bf)
{
  int idx = blockIdx.x * 256 + threadIdx.x;
  if (idx >= 320 * 4096) return;
  int m = idx >> 12, n = idx & 4095;
  float s = b1[n];
  #pragma unroll
  for (int s2 = 0; s2 < 8; ++s2) s += P[(size_t)s2 * 320 * 4096 + idx];
  s = fmaxf(s, 0.f);
  h1bf[idx] = (m < 300) ? f2bf(s) : (unsigned short)0;
}

__global__ __launch_bounds__(256) void k_reduce2(
    const float* __restrict__ P, const float* __restrict__ b2, unsigned short* __restrict__ fc7bf)
{
  int idx = blockIdx.x * 256 + threadIdx.x;
  if (idx >= 300 * 4096) return;
  int n = idx & 4095;
  float s = b2[n];
  #pragma unroll
  for (int s2 = 0; s2 < 8; ++s2) s += P[(size_t)s2 * 320 * 4096 + idx];
  fc7bf[idx] = f2bf(fmaxf(s, 0.f));
}

// ===========================================================================
extern "C" void kernel_launch(void* const* d_in, const int* in_sizes, int n_in,
                              void* d_out, int out_size, void* d_ws, size_t ws_size,
                              hipStream_t stream)
{
  const float* x    = (const float*)d_in[0];
  const float* Wext = (const float*)d_in[1];
  const float* Wc1  = (const float*)d_in[2];
  const float* bc1  = (const float*)d_in[3];
  const float* Wloc = (const float*)d_in[4];
  const float* bloc = (const float*)d_in[5];
  const float* Wsc  = (const float*)d_in[6];
  const float* bsc  = (const float*)d_in[7];
  const float* W1   = (const float*)d_in[8];
  const float* b1   = (const float*)d_in[9];
  const float* W2   = (const float*)d_in[10];
  const float* b2   = (const float*)d_in[11];
  const float* Wl   = (const float*)d_in[12];
  const float* bl   = (const float*)d_in[13];
  const float* Wsv  = (const float*)d_in[14];
  const float* bs   = (const float*)d_in[15];
  const void*  scalep = d_in[16];
  float* out = (float*)d_out;
  char* ws = (char*)d_ws;

  // All regions dedicated (no aliasing; ws_size ~1.6 GB, usage ~150 MB).
  size_t off = 0;
  auto alloc = [&](size_t b) { size_t o = off; off += (b + 255) & ~(size_t)255; return o; };
  size_t o_featyxc = alloc((size_t)NPOS * 512 * 4);
  size_t o_layer1  = alloc((size_t)NPOS * 512 * 4);
  size_t o_rpnloc  = alloc((size_t)NPOS * 36 * 4);
  size_t o_rpnsc   = alloc((size_t)NPOS * 18 * 4);
  size_t o_roiall  = alloc((size_t)NANCH * 16);
  size_t o_keys    = alloc((size_t)NANCH * 8);
  size_t o_boxes   = alloc((size_t)PRE * 16);
  size_t o_vbs     = alloc((size_t)PRE * 4);
  size_t o_supmat  = alloc((size_t)PRE * 32 * 8);
  size_t o_rois    = alloc((size_t)POST * 16);
  size_t o_poolbf  = alloc((size_t)320 * 25088 * 2);
  size_t o_h1bf    = alloc((size_t)320 * 4096 * 2);
  size_t o_wcat    = alloc((size_t)4096 * 128 * 2);
  size_t o_wc1p    = alloc((size_t)512 * 4608 * 4);
  size_t o_cpart   = alloc((size_t)8 * NPOS * 512 * 4);
  size_t o_part    = alloc((size_t)8 * 320 * 4096 * 4);
  (void)ws_size; (void)in_sizes; (void)n_in; (void)out_size;

  float* feat_yxc = (float*)(ws + o_featyxc);
  float* layer1   = (float*)(ws + o_layer1);
  float* rpnloc   = (float*)(ws + o_rpnloc);
  float* rpnsc    = (float*)(ws + o_rpnsc);
  float4* roi_all = (float4*)(ws + o_roiall);
  unsigned long long* keys = (unsigned long long*)(ws + o_keys);
  float4* boxes   = (float4*)(ws + o_boxes);
  int* vbs        = (int*)(ws + o_vbs);
  unsigned long long* supmat = (unsigned long long*)(ws + o_supmat);
  float* rois     = (float*)(ws + o_rois);
  unsigned short* poolbf = (unsigned short*)(ws + o_poolbf);
  unsigned short* h1bf   = (unsigned short*)(ws + o_h1bf);
  unsigned short* wcat   = (unsigned short*)(ws + o_wcat);
  float* wc1p     = (float*)(ws + o_wc1p);
  float* cpart    = (float*)(ws + o_cpart);
  float* partials = (float*)(ws + o_part);

  // weight packs (independent)
  k_wpack<<<(4096 * 128) / 256, 256, 0, stream>>>(Wl, Wsv, wcat);
  k_wc1pack<<<512, 256, 0, stream>>>(Wc1, wc1p);
  // feature extractor (fused A-read from x) + relu  [split-K=4]
  k_gemm_conv<0><<<dim3(19, 8, 4), 256, 0, stream>>>(x, Wext, cpart, 192);
  k_reduce_conv<false, 4><<<(NPOS * 128 + 255) / 256, 256, 0, stream>>>(cpart, nullptr, feat_yxc);
  // 3x3 conv 512->512 SAME (fused A-read from feat_yxc, k'=r*512+ci) [split-K=8]
  k_gemm_conv<1><<<dim3(19, 8, 8), 256, 0, stream>>>(feat_yxc, wc1p, cpart, 576);
  k_reduce_conv<true, 8><<<(NPOS * 128 + 255) / 256, 256, 0, stream>>>(cpart, bc1, layer1);
  // merged RPN 1x1 convs (fp32, score exactness)
  k_gemm_rpn<<<38, 256, 0, stream>>>(layer1, Wloc, Wsc, bloc, bsc, rpnloc, rpnsc);
  // proposals -> top-2000 -> NMS -> rois
  k_proposal<<<(NANCH + 255) / 256, 256, 0, stream>>>(rpnloc, rpnsc, scalep, roi_all, keys);
  k_topk<<<1, 1024, 0, stream>>>(keys, roi_all, boxes, vbs);
  k_supmat<<<PRE, 64, 0, stream>>>(boxes, supmat);
  k_nms<<<1, 256, 0, stream>>>(supmat, vbs, boxes, rois, out + 31500);
  // ROI max-pool -> bf16 pool rows 0..299 (rows 300..319 discarded by reduce1)
  k_roipool<<<dim3(POST, 8), 256, 0, stream>>>(feat_yxc, rois, poolbf);
  // FC1 -> relu -> FC2 -> relu -> heads (bf16 MFMA, split-K=8)
  k_fcg<false><<<dim3(32, 2, 8), 512, 0, stream>>>(poolbf, W1, partials, 25088, 4096);
  k_reduce1<<<(320 * 4096) / 256, 256, 0, stream>>>(partials, b1, h1bf);
  k_fcg<false><<<dim3(32, 2, 8), 512, 0, stream>>>(h1bf, W2, partials, 4096, 4096);
  k_reduce2<<<(300 * 4096) / 256, 256, 0, stream>>>(partials, b2, h1bf);
  k_fcg<true><<<dim3(1, 2, 8), 512, 0, stream>>>(h1bf, wcat, partials, 4096, 128);
  k_headreduce<<<(300 * 105 + 255) / 256, 256, 0, stream>>>(partials, bl, bs, out);
}